// Round 2
// baseline (640.809 us; speedup 1.0000x reference)
//
#include <hip/hip_runtime.h>

#define N_NODES   50000
#define N_EDGES   800000
#define HID       128
#define OUT_DIM   64
#define NUM_GRAPHS 512
#define EPS       1e-6f

static __device__ __forceinline__ float signpow(float x, bool sqrt_mode) {
    // sign(x) * (|x|+EPS)^p ; p==2 (sqrt_mode=false) or p==0.5 (sqrt_mode=true)
    if (x == 0.0f) return 0.0f;
    float a = fabsf(x) + EPS;
    float v = sqrt_mode ? sqrtf(a) : a * a;
    return x > 0.0f ? v : -v;
}

// ---- CSR build ------------------------------------------------------------
__global__ void k_count(const int* __restrict__ ei, int* __restrict__ cnt) {
    int e = blockIdx.x * blockDim.x + threadIdx.x;
    if (e < N_EDGES) atomicAdd(&cnt[ei[N_EDGES + e]], 1);
}

__global__ __launch_bounds__(1024) void k_scan(const int* __restrict__ cnt, int* __restrict__ offs) {
    __shared__ int part[1024];
    int tid = threadIdx.x;
    const int chunk = (N_NODES + 1023) / 1024;
    int start = tid * chunk;
    int end   = start + chunk; if (end > N_NODES) end = N_NODES; if (start > N_NODES) start = N_NODES;
    int s = 0;
    for (int i = start; i < end; i++) s += cnt[i];
    part[tid] = s;
    __syncthreads();
    for (int off = 1; off < 1024; off <<= 1) {
        int v = (tid >= off) ? part[tid - off] : 0;
        __syncthreads();
        part[tid] += v;
        __syncthreads();
    }
    int run = (tid == 0) ? 0 : part[tid - 1];
    for (int i = start; i < end; i++) { offs[i] = run; run += cnt[i]; }
    if (tid == 1023) offs[N_NODES] = part[1023];
}

__global__ void k_dis(const int* __restrict__ cnt, float* __restrict__ dis) {
    int n = blockIdx.x * blockDim.x + threadIdx.x;
    if (n < N_NODES) dis[n] = rsqrtf((float)cnt[n] + 1.0f);
}

__global__ void k_fill(const int* __restrict__ ei, const int* __restrict__ offs,
                       int* __restrict__ fillpos, int* __restrict__ csr_src) {
    int e = blockIdx.x * blockDim.x + threadIdx.x;
    if (e >= N_EDGES) return;
    int s = ei[e];
    int d = ei[N_EDGES + e];
    int p = atomicAdd(&fillpos[d], 1);
    csr_src[offs[d] + p] = s;
}

// ---- fp32 GEMM: out[M x 128] = A[M x 128] @ W[128 x 128] ------------------
__global__ __launch_bounds__(256) void k_gemm128(const float* __restrict__ A,
                                                 const float* __restrict__ W,
                                                 float* __restrict__ out, int M) {
    __shared__ float hs[64][128];   // 32 KB
    __shared__ float Ws[64][128];   // 32 KB
    int t = threadIdx.x;
    int block_row = blockIdx.x * 64;

    // load A tile (64 rows x 128 cols) as float4
    for (int i = t; i < 2048; i += 256) {
        int r = i >> 5, c4 = i & 31;
        int gr = block_row + r;
        float4 v = make_float4(0.f, 0.f, 0.f, 0.f);
        if (gr < M) v = ((const float4*)A)[gr * 32 + c4];
        ((float4*)hs)[i] = v;
    }

    int tx = t & 31, ty = t >> 5;    // tx: 32 col-groups of 4, ty: 8 row-groups of 8
    int c0 = tx * 4;
    int r0 = ty * 8;
    float acc[8][4] = {};

    for (int kb = 0; kb < 2; kb++) {
        for (int i = t; i < 2048; i += 256)
            ((float4*)Ws)[i] = ((const float4*)W)[kb * 2048 + i];
        __syncthreads();
        #pragma unroll 16
        for (int kk = 0; kk < 64; kk++) {
            int k = kb * 64 + kk;
            float4 w = *(const float4*)&Ws[kk][c0];
            #pragma unroll
            for (int i = 0; i < 8; i++) {
                float a = hs[r0 + i][k];
                acc[i][0] += a * w.x; acc[i][1] += a * w.y;
                acc[i][2] += a * w.z; acc[i][3] += a * w.w;
            }
        }
        __syncthreads();
    }

    for (int i = 0; i < 8; i++) {
        int gr = block_row + r0 + i;
        if (gr < M) {
            float4 o = make_float4(acc[i][0], acc[i][1], acc[i][2], acc[i][3]);
            *(float4*)&out[gr * 128 + c0] = o;
        }
    }
}

// ---- GCN aggregation: h[n] = relu?( dn*sum_j tmp[s_j]*dis[s_j] + tmp[n]*dn^2 + b )
__global__ __launch_bounds__(256) void k_agg(const float* __restrict__ tmp,
                                             const int* __restrict__ offs,
                                             const int* __restrict__ csr_src,
                                             const float* __restrict__ dis,
                                             const float* __restrict__ bias,
                                             float* __restrict__ hout, int relu) {
    int node = blockIdx.x * 4 + (threadIdx.x >> 6);
    if (node >= N_NODES) return;
    int lane = threadIdx.x & 63;
    int beg = offs[node], end = offs[node + 1];
    float dn = dis[node];
    float ax = 0.f, ay = 0.f;
    for (int j = beg; j < end; j++) {
        int s = csr_src[j];
        float w = dis[s];
        float2 v = *(const float2*)&tmp[s * HID + lane * 2];
        ax = fmaf(v.x, w, ax);
        ay = fmaf(v.y, w, ay);
    }
    float2 self = *(const float2*)&tmp[node * HID + lane * 2];
    float bx = bias[lane * 2], by = bias[lane * 2 + 1];
    float ox = ax * dn + self.x * dn * dn + bx;
    float oy = ay * dn + self.y * dn * dn + by;
    if (relu) { ox = fmaxf(ox, 0.f); oy = fmaxf(oy, 0.f); }
    float2 o = make_float2(ox, oy);
    *(float2*)&hout[node * HID + lane * 2] = o;
}

// ---- graph boundaries from sorted batch ------------------------------------
__global__ void k_bounds(const int* __restrict__ batch, int* __restrict__ gstart) {
    int n = blockIdx.x * blockDim.x + threadIdx.x;
    if (n >= N_NODES) return;
    int b  = batch[n];
    int bp = (n == 0) ? -1 : batch[n - 1];
    for (int g = bp + 1; g <= b; g++) gstart[g] = n;
    if (n == N_NODES - 1)
        for (int g = b + 1; g <= NUM_GRAPHS; g++) gstart[g] = N_NODES;
}

// ---- generalized-mean pool (p=2, sign preserving) + relu -------------------
__global__ __launch_bounds__(256) void k_pool(const float* __restrict__ h,
                                              const int* __restrict__ gstart,
                                              float* __restrict__ pooled) {
    int g = blockIdx.x * 4 + (threadIdx.x >> 6);
    if (g >= NUM_GRAPHS) return;
    int lane = threadIdx.x & 63;
    int beg = gstart[g], end = gstart[g + 1];
    float sx = 0.f, sy = 0.f;
    for (int n = beg; n < end; n++) {
        float2 v = *(const float2*)&h[n * HID + lane * 2];
        sx += signpow(v.x, false);
        sy += signpow(v.y, false);
    }
    float c  = fmaxf((float)(end - beg), 1.0f);
    float px = sx / c, py = sy / c;
    float rx = fmaxf(signpow(px, true), 0.f);
    float ry = fmaxf(signpow(py, true), 0.f);
    pooled[g * HID + lane * 2]     = rx;
    pooled[g * HID + lane * 2 + 1] = ry;
}

// ---- FF head: out = relu(pooled@Wf0+bf0) @ Wf1 + bf1 -----------------------
__global__ __launch_bounds__(128) void k_ff(const float* __restrict__ pooled,
                                            const float* __restrict__ Wf0,
                                            const float* __restrict__ bf0,
                                            const float* __restrict__ Wf1,
                                            const float* __restrict__ bf1,
                                            float* __restrict__ out) {
    __shared__ float row[128];
    __shared__ float zrow[128];
    int g = blockIdx.x, t = threadIdx.x;
    row[t] = pooled[g * HID + t];
    __syncthreads();
    float acc = bf0[t];
    #pragma unroll 8
    for (int k = 0; k < 128; k++) acc = fmaf(row[k], Wf0[k * 128 + t], acc);
    zrow[t] = fmaxf(acc, 0.f);
    __syncthreads();
    if (t < OUT_DIM) {
        float a2 = bf1[t];
        #pragma unroll 8
        for (int k = 0; k < 128; k++) a2 = fmaf(zrow[k], Wf1[k * OUT_DIM + t], a2);
        out[g * OUT_DIM + t] = a2;
    }
}

// ---------------------------------------------------------------------------
static inline size_t align256(size_t x) { return (x + 255) & ~(size_t)255; }

extern "C" void kernel_launch(void* const* d_in, const int* in_sizes, int n_in,
                              void* d_out, int out_size, void* d_ws, size_t ws_size,
                              hipStream_t stream) {
    const float* x     = (const float*)d_in[0];
    const int*   ei    = (const int*)d_in[1];    // int64 in reference -> int32 from harness
    const int*   batch = (const int*)d_in[2];
    const float* W0  = (const float*)d_in[3];  const float* b0  = (const float*)d_in[4];
    const float* W1  = (const float*)d_in[5];  const float* b1  = (const float*)d_in[6];
    const float* W2  = (const float*)d_in[7];  const float* b2  = (const float*)d_in[8];
    const float* Wf0 = (const float*)d_in[9];  const float* bf0 = (const float*)d_in[10];
    const float* Wf1 = (const float*)d_in[11]; const float* bf1 = (const float*)d_in[12];
    float* out = (float*)d_out;

    char* p = (char*)d_ws;
    float* tmp     = (float*)p; p += align256((size_t)N_NODES * HID * 4);
    float* h       = (float*)p; p += align256((size_t)N_NODES * HID * 4);
    int*   cnt     = (int*)p;   p += align256((size_t)N_NODES * 4);
    int*   offs    = (int*)p;   p += align256((size_t)(N_NODES + 1) * 4);
    int*   fillpos = (int*)p;   p += align256((size_t)N_NODES * 4);
    int*   csr     = (int*)p;   p += align256((size_t)N_EDGES * 4);
    float* dis     = (float*)p; p += align256((size_t)N_NODES * 4);
    int*   gstart  = (int*)p;   p += align256((size_t)(NUM_GRAPHS + 1) * 4);
    float* pooled  = (float*)p; p += align256((size_t)NUM_GRAPHS * HID * 4);

    hipMemsetAsync(cnt, 0, (size_t)N_NODES * 4, stream);
    hipMemsetAsync(fillpos, 0, (size_t)N_NODES * 4, stream);

    const int TB = 256;
    k_count<<<(N_EDGES + TB - 1) / TB, TB, 0, stream>>>(ei, cnt);
    k_scan<<<1, 1024, 0, stream>>>(cnt, offs);
    k_dis<<<(N_NODES + TB - 1) / TB, TB, 0, stream>>>(cnt, dis);
    k_fill<<<(N_EDGES + TB - 1) / TB, TB, 0, stream>>>(ei, offs, fillpos, csr);

    int gemm_blocks = (N_NODES + 63) / 64;
    int agg_blocks  = (N_NODES + 3) / 4;

    // layer 0: x -> h (relu)
    k_gemm128<<<gemm_blocks, 256, 0, stream>>>(x, W0, tmp, N_NODES);
    k_agg<<<agg_blocks, 256, 0, stream>>>(tmp, offs, csr, dis, b0, h, 1);
    // layer 1: h -> h (relu)
    k_gemm128<<<gemm_blocks, 256, 0, stream>>>(h, W1, tmp, N_NODES);
    k_agg<<<agg_blocks, 256, 0, stream>>>(tmp, offs, csr, dis, b1, h, 1);
    // layer 2: h -> h (no relu)
    k_gemm128<<<gemm_blocks, 256, 0, stream>>>(h, W2, tmp, N_NODES);
    k_agg<<<agg_blocks, 256, 0, stream>>>(tmp, offs, csr, dis, b2, h, 0);

    k_bounds<<<(N_NODES + TB - 1) / TB, TB, 0, stream>>>(batch, gstart);
    k_pool<<<(NUM_GRAPHS + 3) / 4, 256, 0, stream>>>(h, gstart, pooled);
    k_ff<<<NUM_GRAPHS, 128, 0, stream>>>(pooled, Wf0, bf0, Wf1, bf1, out);
}

// Round 3
// 559.290 us; speedup vs baseline: 1.1458x; 1.1458x over previous
//
#include <hip/hip_runtime.h>

#define N_NODES   50000
#define N_EDGES   800000
#define HID       128
#define OUT_DIM   64
#define NUM_GRAPHS 512
#define EPS       1e-6f

static __device__ __forceinline__ float signpow(float x, bool sqrt_mode) {
    if (x == 0.0f) return 0.0f;
    float a = fabsf(x) + EPS;
    float v = sqrt_mode ? sqrtf(a) : a * a;
    return x > 0.0f ? v : -v;
}

// ---- CSR build ------------------------------------------------------------
__global__ void k_count(const int* __restrict__ ei, int* __restrict__ cnt) {
    int e = blockIdx.x * blockDim.x + threadIdx.x;
    if (e < N_EDGES) atomicAdd(&cnt[ei[N_EDGES + e]], 1);
}

__global__ __launch_bounds__(1024) void k_scan(const int* __restrict__ cnt, int* __restrict__ offs) {
    __shared__ int part[1024];
    int tid = threadIdx.x;
    const int chunk = (N_NODES + 1023) / 1024;
    int start = tid * chunk;
    int end   = start + chunk; if (end > N_NODES) end = N_NODES; if (start > N_NODES) start = N_NODES;
    int s = 0;
    for (int i = start; i < end; i++) s += cnt[i];
    part[tid] = s;
    __syncthreads();
    for (int off = 1; off < 1024; off <<= 1) {
        int v = (tid >= off) ? part[tid - off] : 0;
        __syncthreads();
        part[tid] += v;
        __syncthreads();
    }
    int run = (tid == 0) ? 0 : part[tid - 1];
    for (int i = start; i < end; i++) { offs[i] = run; run += cnt[i]; }
    if (tid == 1023) offs[N_NODES] = part[1023];
}

__global__ void k_dis(const int* __restrict__ cnt, float* __restrict__ dis) {
    int n = blockIdx.x * blockDim.x + threadIdx.x;
    if (n < N_NODES) dis[n] = rsqrtf((float)cnt[n] + 1.0f);
}

__global__ void k_fill(const int* __restrict__ ei, const int* __restrict__ offs,
                       int* __restrict__ fillpos, int* __restrict__ csr_src) {
    int e = blockIdx.x * blockDim.x + threadIdx.x;
    if (e >= N_EDGES) return;
    int s = ei[e];
    int d = ei[N_EDGES + e];
    int p = atomicAdd(&fillpos[d], 1);
    csr_src[offs[d] + p] = s;
}

// ---- fp32 GEMM: out[M x 128] = (A[M x 128] @ W[128 x 128]) * scale[row]? --
__global__ __launch_bounds__(256) void k_gemm128(const float* __restrict__ A,
                                                 const float* __restrict__ W,
                                                 float* __restrict__ out, int M,
                                                 const float* __restrict__ scale) {
    __shared__ float hs[64][128];   // 32 KB
    __shared__ float Ws[64][128];   // 32 KB
    int t = threadIdx.x;
    int block_row = blockIdx.x * 64;

    for (int i = t; i < 2048; i += 256) {
        int r = i >> 5, c4 = i & 31;
        int gr = block_row + r;
        float4 v = make_float4(0.f, 0.f, 0.f, 0.f);
        if (gr < M) v = ((const float4*)A)[gr * 32 + c4];
        ((float4*)hs)[i] = v;
    }

    int tx = t & 31, ty = t >> 5;
    int c0 = tx * 4;
    int r0 = ty * 8;
    float acc[8][4] = {};

    for (int kb = 0; kb < 2; kb++) {
        for (int i = t; i < 2048; i += 256)
            ((float4*)Ws)[i] = ((const float4*)W)[kb * 2048 + i];
        __syncthreads();
        #pragma unroll 16
        for (int kk = 0; kk < 64; kk++) {
            int k = kb * 64 + kk;
            float4 w = *(const float4*)&Ws[kk][c0];
            #pragma unroll
            for (int i = 0; i < 8; i++) {
                float a = hs[r0 + i][k];
                acc[i][0] += a * w.x; acc[i][1] += a * w.y;
                acc[i][2] += a * w.z; acc[i][3] += a * w.w;
            }
        }
        __syncthreads();
    }

    for (int i = 0; i < 8; i++) {
        int gr = block_row + r0 + i;
        if (gr < M) {
            float s = scale ? scale[gr] : 1.0f;
            float4 o = make_float4(acc[i][0] * s, acc[i][1] * s,
                                   acc[i][2] * s, acc[i][3] * s);
            *(float4*)&out[gr * 128 + c0] = o;
        }
    }
}

// ---- GCN aggregation on pre-scaled features --------------------------------
// tmpS[n] = (h@W)[n] * dis[n];  out[n] = relu?( (sum_{s in N(n)} tmpS[s] + tmpS[n]) * dn + b )
__global__ __launch_bounds__(256) void k_agg(const float* __restrict__ tmpS,
                                             const int* __restrict__ offs,
                                             const int* __restrict__ csr_src,
                                             const float* __restrict__ dis,
                                             const float* __restrict__ bias,
                                             float* __restrict__ hout, int relu) {
    int node = blockIdx.x * 4 + (threadIdx.x >> 6);
    if (node >= N_NODES) return;
    int lane = threadIdx.x & 63;
    int beg = offs[node], end = offs[node + 1];
    float dn = dis[node];
    // issue self-row load early
    float2 self = *(const float2*)&tmpS[node * HID + lane * 2];

    float ax0 = 0.f, ay0 = 0.f, ax1 = 0.f, ay1 = 0.f;
    float ax2 = 0.f, ay2 = 0.f, ax3 = 0.f, ay3 = 0.f;
    int j = beg;
    for (; j + 4 <= end; j += 4) {
        int s0 = csr_src[j];
        int s1 = csr_src[j + 1];
        int s2 = csr_src[j + 2];
        int s3 = csr_src[j + 3];
        float2 v0 = *(const float2*)&tmpS[s0 * HID + lane * 2];
        float2 v1 = *(const float2*)&tmpS[s1 * HID + lane * 2];
        float2 v2 = *(const float2*)&tmpS[s2 * HID + lane * 2];
        float2 v3 = *(const float2*)&tmpS[s3 * HID + lane * 2];
        ax0 += v0.x; ay0 += v0.y;
        ax1 += v1.x; ay1 += v1.y;
        ax2 += v2.x; ay2 += v2.y;
        ax3 += v3.x; ay3 += v3.y;
    }
    for (; j < end; j++) {
        int s = csr_src[j];
        float2 v = *(const float2*)&tmpS[s * HID + lane * 2];
        ax0 += v.x; ay0 += v.y;
    }
    float ax = (ax0 + ax1) + (ax2 + ax3);
    float ay = (ay0 + ay1) + (ay2 + ay3);

    float bx = bias[lane * 2], by = bias[lane * 2 + 1];
    float ox = (ax + self.x) * dn + bx;
    float oy = (ay + self.y) * dn + by;
    if (relu) { ox = fmaxf(ox, 0.f); oy = fmaxf(oy, 0.f); }
    float2 o = make_float2(ox, oy);
    *(float2*)&hout[node * HID + lane * 2] = o;
}

// ---- graph boundaries from sorted batch ------------------------------------
__global__ void k_bounds(const int* __restrict__ batch, int* __restrict__ gstart) {
    int n = blockIdx.x * blockDim.x + threadIdx.x;
    if (n >= N_NODES) return;
    int b  = batch[n];
    int bp = (n == 0) ? -1 : batch[n - 1];
    for (int g = bp + 1; g <= b; g++) gstart[g] = n;
    if (n == N_NODES - 1)
        for (int g = b + 1; g <= NUM_GRAPHS; g++) gstart[g] = N_NODES;
}

// ---- generalized-mean pool (p=2, sign preserving) + relu -------------------
__global__ __launch_bounds__(256) void k_pool(const float* __restrict__ h,
                                              const int* __restrict__ gstart,
                                              float* __restrict__ pooled) {
    int g = blockIdx.x * 4 + (threadIdx.x >> 6);
    if (g >= NUM_GRAPHS) return;
    int lane = threadIdx.x & 63;
    int beg = gstart[g], end = gstart[g + 1];
    float sx = 0.f, sy = 0.f;
    for (int n = beg; n < end; n++) {
        float2 v = *(const float2*)&h[n * HID + lane * 2];
        sx += signpow(v.x, false);
        sy += signpow(v.y, false);
    }
    float c  = fmaxf((float)(end - beg), 1.0f);
    float px = sx / c, py = sy / c;
    float rx = fmaxf(signpow(px, true), 0.f);
    float ry = fmaxf(signpow(py, true), 0.f);
    pooled[g * HID + lane * 2]     = rx;
    pooled[g * HID + lane * 2 + 1] = ry;
}

// ---- FF head: out = relu(pooled@Wf0+bf0) @ Wf1 + bf1 -----------------------
__global__ __launch_bounds__(128) void k_ff(const float* __restrict__ pooled,
                                            const float* __restrict__ Wf0,
                                            const float* __restrict__ bf0,
                                            const float* __restrict__ Wf1,
                                            const float* __restrict__ bf1,
                                            float* __restrict__ out) {
    __shared__ float row[128];
    __shared__ float zrow[128];
    int g = blockIdx.x, t = threadIdx.x;
    row[t] = pooled[g * HID + t];
    __syncthreads();
    float acc = bf0[t];
    #pragma unroll 8
    for (int k = 0; k < 128; k++) acc = fmaf(row[k], Wf0[k * 128 + t], acc);
    zrow[t] = fmaxf(acc, 0.f);
    __syncthreads();
    if (t < OUT_DIM) {
        float a2 = bf1[t];
        #pragma unroll 8
        for (int k = 0; k < 128; k++) a2 = fmaf(zrow[k], Wf1[k * OUT_DIM + t], a2);
        out[g * OUT_DIM + t] = a2;
    }
}

// ---------------------------------------------------------------------------
static inline size_t align256(size_t x) { return (x + 255) & ~(size_t)255; }

extern "C" void kernel_launch(void* const* d_in, const int* in_sizes, int n_in,
                              void* d_out, int out_size, void* d_ws, size_t ws_size,
                              hipStream_t stream) {
    const float* x     = (const float*)d_in[0];
    const int*   ei    = (const int*)d_in[1];    // int64 in reference -> int32 from harness
    const int*   batch = (const int*)d_in[2];
    const float* W0  = (const float*)d_in[3];  const float* b0  = (const float*)d_in[4];
    const float* W1  = (const float*)d_in[5];  const float* b1  = (const float*)d_in[6];
    const float* W2  = (const float*)d_in[7];  const float* b2  = (const float*)d_in[8];
    const float* Wf0 = (const float*)d_in[9];  const float* bf0 = (const float*)d_in[10];
    const float* Wf1 = (const float*)d_in[11]; const float* bf1 = (const float*)d_in[12];
    float* out = (float*)d_out;

    char* p = (char*)d_ws;
    float* tmp     = (float*)p; p += align256((size_t)N_NODES * HID * 4);
    float* h       = (float*)p; p += align256((size_t)N_NODES * HID * 4);
    int*   cnt     = (int*)p;   p += align256((size_t)N_NODES * 4);
    int*   offs    = (int*)p;   p += align256((size_t)(N_NODES + 1) * 4);
    int*   fillpos = (int*)p;   p += align256((size_t)N_NODES * 4);
    int*   csr     = (int*)p;   p += align256((size_t)N_EDGES * 4);
    float* dis     = (float*)p; p += align256((size_t)N_NODES * 4);
    int*   gstart  = (int*)p;   p += align256((size_t)(NUM_GRAPHS + 1) * 4);
    float* pooled  = (float*)p; p += align256((size_t)NUM_GRAPHS * HID * 4);

    hipMemsetAsync(cnt, 0, (size_t)N_NODES * 4, stream);
    hipMemsetAsync(fillpos, 0, (size_t)N_NODES * 4, stream);

    const int TB = 256;
    k_count<<<(N_EDGES + TB - 1) / TB, TB, 0, stream>>>(ei, cnt);
    k_scan<<<1, 1024, 0, stream>>>(cnt, offs);
    k_dis<<<(N_NODES + TB - 1) / TB, TB, 0, stream>>>(cnt, dis);
    k_fill<<<(N_EDGES + TB - 1) / TB, TB, 0, stream>>>(ei, offs, fillpos, csr);

    int gemm_blocks = (N_NODES + 63) / 64;
    int agg_blocks  = (N_NODES + 3) / 4;

    // layer 0: x -> h (relu) ; GEMM writes tmp scaled by dis[row]
    k_gemm128<<<gemm_blocks, 256, 0, stream>>>(x, W0, tmp, N_NODES, dis);
    k_agg<<<agg_blocks, 256, 0, stream>>>(tmp, offs, csr, dis, b0, h, 1);
    // layer 1
    k_gemm128<<<gemm_blocks, 256, 0, stream>>>(h, W1, tmp, N_NODES, dis);
    k_agg<<<agg_blocks, 256, 0, stream>>>(tmp, offs, csr, dis, b1, h, 1);
    // layer 2 (no relu)
    k_gemm128<<<gemm_blocks, 256, 0, stream>>>(h, W2, tmp, N_NODES, dis);
    k_agg<<<agg_blocks, 256, 0, stream>>>(tmp, offs, csr, dis, b2, h, 0);

    k_bounds<<<(N_NODES + TB - 1) / TB, TB, 0, stream>>>(batch, gstart);
    k_pool<<<(NUM_GRAPHS + 3) / 4, 256, 0, stream>>>(h, gstart, pooled);
    k_ff<<<NUM_GRAPHS, 128, 0, stream>>>(pooled, Wf0, bf0, Wf1, bf1, out);
}

// Round 4
// 485.928 us; speedup vs baseline: 1.3187x; 1.1510x over previous
//
#include <hip/hip_runtime.h>

#define N_NODES   50000
#define N_EDGES   800000
#define HID       128
#define OUT_DIM   64
#define NUM_GRAPHS 512
#define EPS       1e-6f
#define SCAN_NB   ((N_NODES + 255) / 256)   // 196

static __device__ __forceinline__ float signpow(float x, bool sqrt_mode) {
    if (x == 0.0f) return 0.0f;
    float a = fabsf(x) + EPS;
    float v = sqrt_mode ? sqrtf(a) : a * a;
    return x > 0.0f ? v : -v;
}

// ---- CSR build ------------------------------------------------------------
__global__ void k_count(const int* __restrict__ ei, int* __restrict__ cnt) {
    int e = blockIdx.x * blockDim.x + threadIdx.x;
    if (e < N_EDGES) atomicAdd(&cnt[ei[N_EDGES + e]], 1);
}

// partial sums: bsum[b] = sum of cnt[b*256 .. b*256+255]
__global__ __launch_bounds__(256) void k_scan_part(const int* __restrict__ cnt,
                                                   int* __restrict__ bsum) {
    __shared__ int sm[256];
    int t = threadIdx.x, i = blockIdx.x * 256 + t;
    sm[t] = (i < N_NODES) ? cnt[i] : 0;
    __syncthreads();
    for (int off = 128; off > 0; off >>= 1) {
        if (t < off) sm[t] += sm[t + off];
        __syncthreads();
    }
    if (t == 0) bsum[blockIdx.x] = sm[0];
}

// exclusive scan of the SCAN_NB block sums (one block)
__global__ __launch_bounds__(256) void k_scan_base(const int* __restrict__ bsum,
                                                   int* __restrict__ bbase) {
    __shared__ int sm[256];
    int t = threadIdx.x;
    int v = (t < SCAN_NB) ? bsum[t] : 0;
    sm[t] = v;
    __syncthreads();
    for (int off = 1; off < 256; off <<= 1) {
        int u = (t >= off) ? sm[t - off] : 0;
        __syncthreads();
        sm[t] += u;
        __syncthreads();
    }
    if (t < SCAN_NB) bbase[t] = sm[t] - v;   // exclusive
}

// final: offs[i] = bbase[b] + intra-block exclusive scan; also dis[i]
__global__ __launch_bounds__(256) void k_scan_final(const int* __restrict__ cnt,
                                                    const int* __restrict__ bbase,
                                                    int* __restrict__ offs,
                                                    float* __restrict__ dis) {
    __shared__ int sm[256];
    int t = threadIdx.x, i = blockIdx.x * 256 + t;
    int c = (i < N_NODES) ? cnt[i] : 0;
    sm[t] = c;
    __syncthreads();
    for (int off = 1; off < 256; off <<= 1) {
        int u = (t >= off) ? sm[t - off] : 0;
        __syncthreads();
        sm[t] += u;
        __syncthreads();
    }
    if (i < N_NODES) {
        offs[i] = bbase[blockIdx.x] + sm[t] - c;   // exclusive prefix
        dis[i]  = rsqrtf((float)c + 1.0f);
    }
    if (blockIdx.x == 0 && t == 0) offs[N_NODES] = N_EDGES;
}

__global__ void k_fill(const int* __restrict__ ei, const int* __restrict__ offs,
                       int* __restrict__ fillpos, int* __restrict__ csr_src) {
    int e = blockIdx.x * blockDim.x + threadIdx.x;
    if (e >= N_EDGES) return;
    int s = ei[e];
    int d = ei[N_EDGES + e];
    int p = atomicAdd(&fillpos[d], 1);
    csr_src[offs[d] + p] = s;
}

// ---- fp32 GEMM: out[M x 128] = (A[M x 128] @ W[128 x 128]) * scale[row]? --
__global__ __launch_bounds__(256) void k_gemm128(const float* __restrict__ A,
                                                 const float* __restrict__ W,
                                                 float* __restrict__ out, int M,
                                                 const float* __restrict__ scale) {
    __shared__ float hs[64][128];   // 32 KB
    __shared__ float Ws[64][128];   // 32 KB
    int t = threadIdx.x;
    int block_row = blockIdx.x * 64;

    for (int i = t; i < 2048; i += 256) {
        int r = i >> 5, c4 = i & 31;
        int gr = block_row + r;
        float4 v = make_float4(0.f, 0.f, 0.f, 0.f);
        if (gr < M) v = ((const float4*)A)[gr * 32 + c4];
        ((float4*)hs)[i] = v;
    }

    int tx = t & 31, ty = t >> 5;
    int c0 = tx * 4;
    int r0 = ty * 8;
    float acc[8][4] = {};

    for (int kb = 0; kb < 2; kb++) {
        for (int i = t; i < 2048; i += 256)
            ((float4*)Ws)[i] = ((const float4*)W)[kb * 2048 + i];
        __syncthreads();
        #pragma unroll 16
        for (int kk = 0; kk < 64; kk++) {
            int k = kb * 64 + kk;
            float4 w = *(const float4*)&Ws[kk][c0];
            #pragma unroll
            for (int i = 0; i < 8; i++) {
                float a = hs[r0 + i][k];
                acc[i][0] += a * w.x; acc[i][1] += a * w.y;
                acc[i][2] += a * w.z; acc[i][3] += a * w.w;
            }
        }
        __syncthreads();
    }

    for (int i = 0; i < 8; i++) {
        int gr = block_row + r0 + i;
        if (gr < M) {
            float s = scale ? scale[gr] : 1.0f;
            float4 o = make_float4(acc[i][0] * s, acc[i][1] * s,
                                   acc[i][2] * s, acc[i][3] * s);
            *(float4*)&out[gr * 128 + c0] = o;
        }
    }
}

// ---- GCN aggregation on pre-scaled features --------------------------------
// tmpS[n] = (h@W)[n] * dis[n];  out[n] = relu?( (sum_{s in N(n)} tmpS[s] + tmpS[n]) * dn + b )
__global__ __launch_bounds__(256) void k_agg(const float* __restrict__ tmpS,
                                             const int* __restrict__ offs,
                                             const int* __restrict__ csr_src,
                                             const float* __restrict__ dis,
                                             const float* __restrict__ bias,
                                             float* __restrict__ hout, int relu) {
    int node = blockIdx.x * 4 + (threadIdx.x >> 6);
    if (node >= N_NODES) return;
    int lane = threadIdx.x & 63;
    int beg = offs[node], end = offs[node + 1];
    float dn = dis[node];
    float2 self = *(const float2*)&tmpS[node * HID + lane * 2];

    float ax[8] = {}, ay[8] = {};
    for (int j = beg; j < end; j += 8) {
        #pragma unroll
        for (int k = 0; k < 8; k++) {
            int jj = j + k < end ? j + k : end - 1;     // clamp (end > beg guaranteed by loop entry)
            int s = csr_src[jj];
            float2 v = *(const float2*)&tmpS[s * HID + lane * 2];
            float m = (j + k < end) ? 1.0f : 0.0f;
            ax[k] = fmaf(v.x, m, ax[k]);
            ay[k] = fmaf(v.y, m, ay[k]);
        }
    }
    float axs = ((ax[0] + ax[1]) + (ax[2] + ax[3])) + ((ax[4] + ax[5]) + (ax[6] + ax[7]));
    float ays = ((ay[0] + ay[1]) + (ay[2] + ay[3])) + ((ay[4] + ay[5]) + (ay[6] + ay[7]));

    float bx = bias[lane * 2], by = bias[lane * 2 + 1];
    float ox = (axs + self.x) * dn + bx;
    float oy = (ays + self.y) * dn + by;
    if (relu) { ox = fmaxf(ox, 0.f); oy = fmaxf(oy, 0.f); }
    float2 o = make_float2(ox, oy);
    *(float2*)&hout[node * HID + lane * 2] = o;
}

// ---- graph boundaries from sorted batch ------------------------------------
__global__ void k_bounds(const int* __restrict__ batch, int* __restrict__ gstart) {
    int n = blockIdx.x * blockDim.x + threadIdx.x;
    if (n >= N_NODES) return;
    int b  = batch[n];
    int bp = (n == 0) ? -1 : batch[n - 1];
    for (int g = bp + 1; g <= b; g++) gstart[g] = n;
    if (n == N_NODES - 1)
        for (int g = b + 1; g <= NUM_GRAPHS; g++) gstart[g] = N_NODES;
}

// ---- generalized-mean pool (p=2, sign preserving) + relu -------------------
__global__ __launch_bounds__(256) void k_pool(const float* __restrict__ h,
                                              const int* __restrict__ gstart,
                                              float* __restrict__ pooled) {
    int g = blockIdx.x * 4 + (threadIdx.x >> 6);
    if (g >= NUM_GRAPHS) return;
    int lane = threadIdx.x & 63;
    int beg = gstart[g], end = gstart[g + 1];
    float sx = 0.f, sy = 0.f;
    for (int n = beg; n < end; n++) {
        float2 v = *(const float2*)&h[n * HID + lane * 2];
        sx += signpow(v.x, false);
        sy += signpow(v.y, false);
    }
    float c  = fmaxf((float)(end - beg), 1.0f);
    float px = sx / c, py = sy / c;
    float rx = fmaxf(signpow(px, true), 0.f);
    float ry = fmaxf(signpow(py, true), 0.f);
    pooled[g * HID + lane * 2]     = rx;
    pooled[g * HID + lane * 2 + 1] = ry;
}

// ---- FF head: out = relu(pooled@Wf0+bf0) @ Wf1 + bf1 -----------------------
__global__ __launch_bounds__(128) void k_ff(const float* __restrict__ pooled,
                                            const float* __restrict__ Wf0,
                                            const float* __restrict__ bf0,
                                            const float* __restrict__ Wf1,
                                            const float* __restrict__ bf1,
                                            float* __restrict__ out) {
    __shared__ float row[128];
    __shared__ float zrow[128];
    int g = blockIdx.x, t = threadIdx.x;
    row[t] = pooled[g * HID + t];
    __syncthreads();
    float acc = bf0[t];
    #pragma unroll 8
    for (int k = 0; k < 128; k++) acc = fmaf(row[k], Wf0[k * 128 + t], acc);
    zrow[t] = fmaxf(acc, 0.f);
    __syncthreads();
    if (t < OUT_DIM) {
        float a2 = bf1[t];
        #pragma unroll 8
        for (int k = 0; k < 128; k++) a2 = fmaf(zrow[k], Wf1[k * OUT_DIM + t], a2);
        out[g * OUT_DIM + t] = a2;
    }
}

// ---------------------------------------------------------------------------
static inline size_t align256(size_t x) { return (x + 255) & ~(size_t)255; }

extern "C" void kernel_launch(void* const* d_in, const int* in_sizes, int n_in,
                              void* d_out, int out_size, void* d_ws, size_t ws_size,
                              hipStream_t stream) {
    const float* x     = (const float*)d_in[0];
    const int*   ei    = (const int*)d_in[1];    // int64 in reference -> int32 from harness
    const int*   batch = (const int*)d_in[2];
    const float* W0  = (const float*)d_in[3];  const float* b0  = (const float*)d_in[4];
    const float* W1  = (const float*)d_in[5];  const float* b1  = (const float*)d_in[6];
    const float* W2  = (const float*)d_in[7];  const float* b2  = (const float*)d_in[8];
    const float* Wf0 = (const float*)d_in[9];  const float* bf0 = (const float*)d_in[10];
    const float* Wf1 = (const float*)d_in[11]; const float* bf1 = (const float*)d_in[12];
    float* out = (float*)d_out;

    char* p = (char*)d_ws;
    float* tmp     = (float*)p; p += align256((size_t)N_NODES * HID * 4);
    float* h       = (float*)p; p += align256((size_t)N_NODES * HID * 4);
    int*   cnt     = (int*)p;   p += align256((size_t)N_NODES * 4);
    int*   offs    = (int*)p;   p += align256((size_t)(N_NODES + 1) * 4);
    int*   fillpos = (int*)p;   p += align256((size_t)N_NODES * 4);
    int*   csr     = (int*)p;   p += align256((size_t)N_EDGES * 4);
    float* dis     = (float*)p; p += align256((size_t)N_NODES * 4);
    int*   gstart  = (int*)p;   p += align256((size_t)(NUM_GRAPHS + 1) * 4);
    float* pooled  = (float*)p; p += align256((size_t)NUM_GRAPHS * HID * 4);
    int*   bsum    = (int*)p;   p += align256((size_t)SCAN_NB * 4);
    int*   bbase   = (int*)p;   p += align256((size_t)SCAN_NB * 4);

    hipMemsetAsync(cnt, 0, (size_t)N_NODES * 4, stream);
    hipMemsetAsync(fillpos, 0, (size_t)N_NODES * 4, stream);

    const int TB = 256;
    k_count<<<(N_EDGES + TB - 1) / TB, TB, 0, stream>>>(ei, cnt);
    k_scan_part <<<SCAN_NB, 256, 0, stream>>>(cnt, bsum);
    k_scan_base <<<1, 256, 0, stream>>>(bsum, bbase);
    k_scan_final<<<SCAN_NB, 256, 0, stream>>>(cnt, bbase, offs, dis);
    k_fill<<<(N_EDGES + TB - 1) / TB, TB, 0, stream>>>(ei, offs, fillpos, csr);

    int gemm_blocks = (N_NODES + 63) / 64;
    int agg_blocks  = (N_NODES + 3) / 4;

    // layer 0: x -> h (relu) ; GEMM writes tmp scaled by dis[row]
    k_gemm128<<<gemm_blocks, 256, 0, stream>>>(x, W0, tmp, N_NODES, dis);
    k_agg<<<agg_blocks, 256, 0, stream>>>(tmp, offs, csr, dis, b0, h, 1);
    // layer 1
    k_gemm128<<<gemm_blocks, 256, 0, stream>>>(h, W1, tmp, N_NODES, dis);
    k_agg<<<agg_blocks, 256, 0, stream>>>(tmp, offs, csr, dis, b1, h, 1);
    // layer 2 (no relu)
    k_gemm128<<<gemm_blocks, 256, 0, stream>>>(h, W2, tmp, N_NODES, dis);
    k_agg<<<agg_blocks, 256, 0, stream>>>(tmp, offs, csr, dis, b2, h, 0);

    k_bounds<<<(N_NODES + TB - 1) / TB, TB, 0, stream>>>(batch, gstart);
    k_pool<<<(NUM_GRAPHS + 3) / 4, 256, 0, stream>>>(h, gstart, pooled);
    k_ff<<<NUM_GRAPHS, 128, 0, stream>>>(pooled, Wf0, bf0, Wf1, bf1, out);
}

// Round 5
// 444.173 us; speedup vs baseline: 1.4427x; 1.0940x over previous
//
#include <hip/hip_runtime.h>

#define N_NODES   50000
#define M_PAD     50048            // 782 * 64
#define N_EDGES   800000
#define HID       128
#define OUT_DIM   64
#define NUM_GRAPHS 512
#define EPS       1e-6f
#define SCAN_NB   ((N_NODES + 255) / 256)   // 196

typedef __attribute__((ext_vector_type(8))) short short8;
typedef __attribute__((ext_vector_type(4))) float f32x4;

static __device__ __forceinline__ unsigned short f2bf(float f) {
    unsigned u = __builtin_bit_cast(unsigned, f);
    u += 0x7FFFu + ((u >> 16) & 1u);           // round-to-nearest-even
    return (unsigned short)(u >> 16);
}
static __device__ __forceinline__ float bf2f(unsigned short h) {
    unsigned u = ((unsigned)h) << 16;
    return __builtin_bit_cast(float, u);
}

static __device__ __forceinline__ float signpow(float x, bool sqrt_mode) {
    if (x == 0.0f) return 0.0f;
    float a = fabsf(x) + EPS;
    float v = sqrt_mode ? sqrtf(a) : a * a;
    return x > 0.0f ? v : -v;
}

// ---- CSR build ------------------------------------------------------------
__global__ void k_count(const int* __restrict__ ei, int* __restrict__ cnt) {
    int e = blockIdx.x * blockDim.x + threadIdx.x;
    if (e < N_EDGES) atomicAdd(&cnt[ei[N_EDGES + e]], 1);
}

__global__ __launch_bounds__(256) void k_scan_part(const int* __restrict__ cnt,
                                                   int* __restrict__ bsum) {
    __shared__ int sm[256];
    int t = threadIdx.x, i = blockIdx.x * 256 + t;
    sm[t] = (i < N_NODES) ? cnt[i] : 0;
    __syncthreads();
    for (int off = 128; off > 0; off >>= 1) {
        if (t < off) sm[t] += sm[t + off];
        __syncthreads();
    }
    if (t == 0) bsum[blockIdx.x] = sm[0];
}

__global__ __launch_bounds__(256) void k_scan_base(const int* __restrict__ bsum,
                                                   int* __restrict__ bbase) {
    __shared__ int sm[256];
    int t = threadIdx.x;
    int v = (t < SCAN_NB) ? bsum[t] : 0;
    sm[t] = v;
    __syncthreads();
    for (int off = 1; off < 256; off <<= 1) {
        int u = (t >= off) ? sm[t - off] : 0;
        __syncthreads();
        sm[t] += u;
        __syncthreads();
    }
    if (t < SCAN_NB) bbase[t] = sm[t] - v;   // exclusive
}

__global__ __launch_bounds__(256) void k_scan_final(const int* __restrict__ cnt,
                                                    const int* __restrict__ bbase,
                                                    int* __restrict__ offs,
                                                    float* __restrict__ dis) {
    __shared__ int sm[256];
    int t = threadIdx.x, i = blockIdx.x * 256 + t;
    int c = (i < N_NODES) ? cnt[i] : 0;
    sm[t] = c;
    __syncthreads();
    for (int off = 1; off < 256; off <<= 1) {
        int u = (t >= off) ? sm[t - off] : 0;
        __syncthreads();
        sm[t] += u;
        __syncthreads();
    }
    if (i < N_NODES) {
        offs[i] = bbase[blockIdx.x] + sm[t] - c;
        dis[i]  = rsqrtf((float)c + 1.0f);
    }
    if (blockIdx.x == 0 && t == 0) offs[N_NODES] = N_EDGES;
}

__global__ void k_fill(const int* __restrict__ ei, const int* __restrict__ offs,
                       int* __restrict__ fillpos, int* __restrict__ csr_src) {
    int e = blockIdx.x * blockDim.x + threadIdx.x;
    if (e >= N_EDGES) return;
    int s = ei[e];
    int d = ei[N_EDGES + e];
    int p = atomicAdd(&fillpos[d], 1);
    csr_src[offs[d] + p] = s;
}

// ---- split fp32 -> (bf16 hi, bf16 lo) -------------------------------------
__global__ void k_split(const float* __restrict__ in, short* __restrict__ hi,
                        short* __restrict__ lo, int n4) {
    int i = blockIdx.x * blockDim.x + threadIdx.x;
    if (i >= n4) return;
    float4 v = ((const float4*)in)[i];
    unsigned short h0 = f2bf(v.x), h1 = f2bf(v.y), h2 = f2bf(v.z), h3 = f2bf(v.w);
    unsigned short l0 = f2bf(v.x - bf2f(h0)), l1 = f2bf(v.y - bf2f(h1));
    unsigned short l2 = f2bf(v.z - bf2f(h2)), l3 = f2bf(v.w - bf2f(h3));
    ushort4 vh; vh.x = h0; vh.y = h1; vh.z = h2; vh.w = h3;
    ushort4 vl; vl.x = l0; vl.y = l1; vl.z = l2; vl.w = l3;
    ((ushort4*)hi)[i] = vh;
    ((ushort4*)lo)[i] = vl;
}

// ---- W[128k x 128n] -> W^T splits: Wt[n][k] hi/lo --------------------------
__global__ void k_wsplit(const float* __restrict__ W, short* __restrict__ Wth,
                         short* __restrict__ Wtl) {
    int tid = blockIdx.x * blockDim.x + threadIdx.x;   // 16384
    int k = tid & 127, n = tid >> 7;
    float w = W[k * HID + n];
    unsigned short h = f2bf(w);
    Wth[n * HID + k] = (short)h;
    Wtl[n * HID + k] = (short)f2bf(w - bf2f(h));
}

// ---- MFMA GEMM: out[M x 128] = (A @ W) * scale[row] ------------------------
// A given as bf16 splits Ah,Al [M_PAD x 128]; W as W^T splits Wh,Wl [128n x 128k].
// A*W ~= Ah*Wh + Al*Wh + Ah*Wl  (fp32 accumulate)
__global__ __launch_bounds__(256) void k_gemm_mfma(const short* __restrict__ Ah,
                                                   const short* __restrict__ Al,
                                                   const short* __restrict__ Wh,
                                                   const short* __restrict__ Wl,
                                                   float* __restrict__ out, int M,
                                                   const float* __restrict__ scale) {
    int wid  = threadIdx.x >> 6;
    int lane = threadIdx.x & 63;
    int row0 = blockIdx.x * 64 + wid * 16;
    int r    = lane & 15;
    int ko   = (lane >> 4) * 8;

    const short* Arh = Ah + (size_t)(row0 + r) * HID;
    const short* Arl = Al + (size_t)(row0 + r) * HID;
    short8 afh[4], afl[4];
    #pragma unroll
    for (int c = 0; c < 4; c++) {
        afh[c] = *(const short8*)(Arh + c * 32 + ko);
        afl[c] = *(const short8*)(Arl + c * 32 + ko);
    }

    f32x4 acc[8];
    #pragma unroll
    for (int n = 0; n < 8; n++) acc[n] = (f32x4){0.f, 0.f, 0.f, 0.f};

    #pragma unroll
    for (int n = 0; n < 8; n++) {
        const short* Wrh = Wh + (size_t)(n * 16 + r) * HID;
        const short* Wrl = Wl + (size_t)(n * 16 + r) * HID;
        #pragma unroll
        for (int c = 0; c < 4; c++) {
            short8 bh = *(const short8*)(Wrh + c * 32 + ko);
            short8 bl = *(const short8*)(Wrl + c * 32 + ko);
            acc[n] = __builtin_amdgcn_mfma_f32_16x16x32_bf16(afh[c], bh, acc[n], 0, 0, 0);
            acc[n] = __builtin_amdgcn_mfma_f32_16x16x32_bf16(afl[c], bh, acc[n], 0, 0, 0);
            acc[n] = __builtin_amdgcn_mfma_f32_16x16x32_bf16(afh[c], bl, acc[n], 0, 0, 0);
        }
    }

    int crow = row0 + (lane >> 4) * 4;
    #pragma unroll
    for (int q = 0; q < 4; q++) {
        int gr = crow + q;
        if (gr < M) {
            float s = scale[gr];
            #pragma unroll
            for (int n = 0; n < 8; n++)
                out[(size_t)gr * HID + n * 16 + (lane & 15)] = acc[n][q] * s;
        }
    }
}

// ---- GCN aggregation on pre-scaled features --------------------------------
// mode 1: relu + write bf16 split pair (hh,hl). mode 0: write fp32 hout, no relu.
__global__ __launch_bounds__(256) void k_agg(const float* __restrict__ tmpS,
                                             const int* __restrict__ offs,
                                             const int* __restrict__ csr_src,
                                             const float* __restrict__ dis,
                                             const float* __restrict__ bias,
                                             float* __restrict__ hout,
                                             short* __restrict__ hh,
                                             short* __restrict__ hl,
                                             int mode) {
    int node = blockIdx.x * 4 + (threadIdx.x >> 6);
    if (node >= N_NODES) return;
    int lane = threadIdx.x & 63;
    int beg = offs[node], end = offs[node + 1];
    float dn = dis[node];
    float2 self = *(const float2*)&tmpS[node * HID + lane * 2];

    float ax[8] = {}, ay[8] = {};
    for (int j = beg; j < end; j += 8) {
        #pragma unroll
        for (int k = 0; k < 8; k++) {
            int jj = j + k < end ? j + k : end - 1;
            int s = csr_src[jj];
            float2 v = *(const float2*)&tmpS[s * HID + lane * 2];
            float m = (j + k < end) ? 1.0f : 0.0f;
            ax[k] = fmaf(v.x, m, ax[k]);
            ay[k] = fmaf(v.y, m, ay[k]);
        }
    }
    float axs = ((ax[0] + ax[1]) + (ax[2] + ax[3])) + ((ax[4] + ax[5]) + (ax[6] + ax[7]));
    float ays = ((ay[0] + ay[1]) + (ay[2] + ay[3])) + ((ay[4] + ay[5]) + (ay[6] + ay[7]));

    float bx = bias[lane * 2], by = bias[lane * 2 + 1];
    float ox = (axs + self.x) * dn + bx;
    float oy = (ays + self.y) * dn + by;
    if (mode == 1) {
        ox = fmaxf(ox, 0.f); oy = fmaxf(oy, 0.f);
        unsigned short hx = f2bf(ox), hy = f2bf(oy);
        ushort2 vh; vh.x = hx; vh.y = hy;
        ushort2 vl; vl.x = f2bf(ox - bf2f(hx)); vl.y = f2bf(oy - bf2f(hy));
        *(ushort2*)&hh[node * HID + lane * 2] = vh;
        *(ushort2*)&hl[node * HID + lane * 2] = vl;
    } else {
        float2 o = make_float2(ox, oy);
        *(float2*)&hout[node * HID + lane * 2] = o;
    }
}

// ---- graph boundaries from sorted batch ------------------------------------
__global__ void k_bounds(const int* __restrict__ batch, int* __restrict__ gstart) {
    int n = blockIdx.x * blockDim.x + threadIdx.x;
    if (n >= N_NODES) return;
    int b  = batch[n];
    int bp = (n == 0) ? -1 : batch[n - 1];
    for (int g = bp + 1; g <= b; g++) gstart[g] = n;
    if (n == N_NODES - 1)
        for (int g = b + 1; g <= NUM_GRAPHS; g++) gstart[g] = N_NODES;
}

// ---- generalized-mean pool (p=2, sign preserving) + relu -------------------
__global__ __launch_bounds__(256) void k_pool(const float* __restrict__ h,
                                              const int* __restrict__ gstart,
                                              float* __restrict__ pooled) {
    int g = blockIdx.x * 4 + (threadIdx.x >> 6);
    if (g >= NUM_GRAPHS) return;
    int lane = threadIdx.x & 63;
    int beg = gstart[g], end = gstart[g + 1];
    float sx = 0.f, sy = 0.f;
    for (int n = beg; n < end; n++) {
        float2 v = *(const float2*)&h[n * HID + lane * 2];
        sx += signpow(v.x, false);
        sy += signpow(v.y, false);
    }
    float c  = fmaxf((float)(end - beg), 1.0f);
    float px = sx / c, py = sy / c;
    float rx = fmaxf(signpow(px, true), 0.f);
    float ry = fmaxf(signpow(py, true), 0.f);
    pooled[g * HID + lane * 2]     = rx;
    pooled[g * HID + lane * 2 + 1] = ry;
}

// ---- FF head ---------------------------------------------------------------
__global__ __launch_bounds__(128) void k_ff(const float* __restrict__ pooled,
                                            const float* __restrict__ Wf0,
                                            const float* __restrict__ bf0,
                                            const float* __restrict__ Wf1,
                                            const float* __restrict__ bf1,
                                            float* __restrict__ out) {
    __shared__ float row[128];
    __shared__ float zrow[128];
    int g = blockIdx.x, t = threadIdx.x;
    row[t] = pooled[g * HID + t];
    __syncthreads();
    float acc = bf0[t];
    #pragma unroll 8
    for (int k = 0; k < 128; k++) acc = fmaf(row[k], Wf0[k * 128 + t], acc);
    zrow[t] = fmaxf(acc, 0.f);
    __syncthreads();
    if (t < OUT_DIM) {
        float a2 = bf1[t];
        #pragma unroll 8
        for (int k = 0; k < 128; k++) a2 = fmaf(zrow[k], Wf1[k * OUT_DIM + t], a2);
        out[g * OUT_DIM + t] = a2;
    }
}

// ---------------------------------------------------------------------------
static inline size_t align256(size_t x) { return (x + 255) & ~(size_t)255; }

extern "C" void kernel_launch(void* const* d_in, const int* in_sizes, int n_in,
                              void* d_out, int out_size, void* d_ws, size_t ws_size,
                              hipStream_t stream) {
    const float* x     = (const float*)d_in[0];
    const int*   ei    = (const int*)d_in[1];
    const int*   batch = (const int*)d_in[2];
    const float* W0  = (const float*)d_in[3];  const float* b0  = (const float*)d_in[4];
    const float* W1  = (const float*)d_in[5];  const float* b1  = (const float*)d_in[6];
    const float* W2  = (const float*)d_in[7];  const float* b2  = (const float*)d_in[8];
    const float* Wf0 = (const float*)d_in[9];  const float* bf0 = (const float*)d_in[10];
    const float* Wf1 = (const float*)d_in[11]; const float* bf1 = (const float*)d_in[12];
    float* out = (float*)d_out;

    char* p = (char*)d_ws;
    float* tmp   = (float*)p; p += align256((size_t)M_PAD * HID * 4);
    short* bufAh = (short*)p; p += align256((size_t)M_PAD * HID * 2);
    short* bufAl = (short*)p; p += align256((size_t)M_PAD * HID * 2);
    short* bufBh = (short*)p; p += align256((size_t)M_PAD * HID * 2);
    short* bufBl = (short*)p; p += align256((size_t)M_PAD * HID * 2);
    float* h     = (float*)bufBh;   // aliases bufBh+bufBl (contiguous 25.6MB), live only after layer2
    int*   cnt     = (int*)p;   p += align256((size_t)N_NODES * 4);
    int*   offs    = (int*)p;   p += align256((size_t)(N_NODES + 1) * 4);
    int*   fillpos = (int*)p;   p += align256((size_t)N_NODES * 4);
    int*   csr     = (int*)p;   p += align256((size_t)N_EDGES * 4);
    float* dis     = (float*)p; p += align256((size_t)N_NODES * 4);
    int*   gstart  = (int*)p;   p += align256((size_t)(NUM_GRAPHS + 1) * 4);
    float* pooled  = (float*)p; p += align256((size_t)NUM_GRAPHS * HID * 4);
    int*   bsum    = (int*)p;   p += align256((size_t)SCAN_NB * 4);
    int*   bbase   = (int*)p;   p += align256((size_t)SCAN_NB * 4);
    short* Wth0    = (short*)p; p += align256((size_t)HID * HID * 2);
    short* Wtl0    = (short*)p; p += align256((size_t)HID * HID * 2);
    short* Wth1    = (short*)p; p += align256((size_t)HID * HID * 2);
    short* Wtl1    = (short*)p; p += align256((size_t)HID * HID * 2);
    short* Wth2    = (short*)p; p += align256((size_t)HID * HID * 2);
    short* Wtl2    = (short*)p; p += align256((size_t)HID * HID * 2);

    hipMemsetAsync(cnt, 0, (size_t)N_NODES * 4, stream);
    hipMemsetAsync(fillpos, 0, (size_t)N_NODES * 4, stream);

    const int TB = 256;
    k_count<<<(N_EDGES + TB - 1) / TB, TB, 0, stream>>>(ei, cnt);
    k_scan_part <<<SCAN_NB, 256, 0, stream>>>(cnt, bsum);
    k_scan_base <<<1, 256, 0, stream>>>(bsum, bbase);
    k_scan_final<<<SCAN_NB, 256, 0, stream>>>(cnt, bbase, offs, dis);
    k_fill<<<(N_EDGES + TB - 1) / TB, TB, 0, stream>>>(ei, offs, fillpos, csr);

    // splits
    int n4 = N_NODES * HID / 4;
    k_split<<<(n4 + TB - 1) / TB, TB, 0, stream>>>(x, bufAh, bufAl, n4);
    k_wsplit<<<64, 256, 0, stream>>>(W0, Wth0, Wtl0);
    k_wsplit<<<64, 256, 0, stream>>>(W1, Wth1, Wtl1);
    k_wsplit<<<64, 256, 0, stream>>>(W2, Wth2, Wtl2);

    int gemm_blocks = M_PAD / 64;             // 782
    int agg_blocks  = (N_NODES + 3) / 4;

    // layer 0
    k_gemm_mfma<<<gemm_blocks, 256, 0, stream>>>(bufAh, bufAl, Wth0, Wtl0, tmp, N_NODES, dis);
    k_agg<<<agg_blocks, 256, 0, stream>>>(tmp, offs, csr, dis, b0, nullptr, bufBh, bufBl, 1);
    // layer 1
    k_gemm_mfma<<<gemm_blocks, 256, 0, stream>>>(bufBh, bufBl, Wth1, Wtl1, tmp, N_NODES, dis);
    k_agg<<<agg_blocks, 256, 0, stream>>>(tmp, offs, csr, dis, b1, nullptr, bufAh, bufAl, 1);
    // layer 2 (no relu, fp32 out for pooling)
    k_gemm_mfma<<<gemm_blocks, 256, 0, stream>>>(bufAh, bufAl, Wth2, Wtl2, tmp, N_NODES, dis);
    k_agg<<<agg_blocks, 256, 0, stream>>>(tmp, offs, csr, dis, b2, h, nullptr, nullptr, 0);

    k_bounds<<<(N_NODES + TB - 1) / TB, TB, 0, stream>>>(batch, gstart);
    k_pool<<<(NUM_GRAPHS + 3) / 4, 256, 0, stream>>>(h, gstart, pooled);
    k_ff<<<NUM_GRAPHS, 128, 0, stream>>>(pooled, Wf0, bf0, Wf1, bf1, out);
}

// Round 6
// 444.130 us; speedup vs baseline: 1.4428x; 1.0001x over previous
//
#include <hip/hip_runtime.h>

#define N_NODES   50000
#define M_PAD     50048            // 782 * 64
#define N_EDGES   800000
#define HID       128
#define OUT_DIM   64
#define NUM_GRAPHS 512
#define EPS       1e-6f
#define SCAN_NB   ((N_NODES + 255) / 256)   // 196

typedef __attribute__((ext_vector_type(8))) short short8;
typedef __attribute__((ext_vector_type(4))) float f32x4;

static __device__ __forceinline__ unsigned short f2bf(float f) {
    unsigned u = __builtin_bit_cast(unsigned, f);
    u += 0x7FFFu + ((u >> 16) & 1u);           // round-to-nearest-even
    return (unsigned short)(u >> 16);
}
static __device__ __forceinline__ float bf2f(unsigned short h) {
    unsigned u = ((unsigned)h) << 16;
    return __builtin_bit_cast(float, u);
}

static __device__ __forceinline__ float signpow(float x, bool sqrt_mode) {
    if (x == 0.0f) return 0.0f;
    float a = fabsf(x) + EPS;
    float v = sqrt_mode ? sqrtf(a) : a * a;
    return x > 0.0f ? v : -v;
}

// ---- CSR build ------------------------------------------------------------
__global__ void k_count(const int* __restrict__ ei, int* __restrict__ cnt) {
    int e = blockIdx.x * blockDim.x + threadIdx.x;
    if (e < N_EDGES) atomicAdd(&cnt[ei[N_EDGES + e]], 1);
}

__global__ __launch_bounds__(256) void k_scan_part(const int* __restrict__ cnt,
                                                   int* __restrict__ bsum) {
    __shared__ int sm[256];
    int t = threadIdx.x, i = blockIdx.x * 256 + t;
    sm[t] = (i < N_NODES) ? cnt[i] : 0;
    __syncthreads();
    for (int off = 128; off > 0; off >>= 1) {
        if (t < off) sm[t] += sm[t + off];
        __syncthreads();
    }
    if (t == 0) bsum[blockIdx.x] = sm[0];
}

__global__ __launch_bounds__(256) void k_scan_base(const int* __restrict__ bsum,
                                                   int* __restrict__ bbase) {
    __shared__ int sm[256];
    int t = threadIdx.x;
    int v = (t < SCAN_NB) ? bsum[t] : 0;
    sm[t] = v;
    __syncthreads();
    for (int off = 1; off < 256; off <<= 1) {
        int u = (t >= off) ? sm[t - off] : 0;
        __syncthreads();
        sm[t] += u;
        __syncthreads();
    }
    if (t < SCAN_NB) bbase[t] = sm[t] - v;   // exclusive
}

__global__ __launch_bounds__(256) void k_scan_final(const int* __restrict__ cnt,
                                                    const int* __restrict__ bbase,
                                                    int* __restrict__ offs,
                                                    float* __restrict__ dis) {
    __shared__ int sm[256];
    int t = threadIdx.x, i = blockIdx.x * 256 + t;
    int c = (i < N_NODES) ? cnt[i] : 0;
    sm[t] = c;
    __syncthreads();
    for (int off = 1; off < 256; off <<= 1) {
        int u = (t >= off) ? sm[t - off] : 0;
        __syncthreads();
        sm[t] += u;
        __syncthreads();
    }
    if (i < N_NODES) {
        offs[i] = bbase[blockIdx.x] + sm[t] - c;
        dis[i]  = rsqrtf((float)c + 1.0f);
    }
    if (blockIdx.x == 0 && t == 0) offs[N_NODES] = N_EDGES;
}

__global__ void k_fill(const int* __restrict__ ei, const int* __restrict__ offs,
                       int* __restrict__ fillpos, int* __restrict__ csr_src) {
    int e = blockIdx.x * blockDim.x + threadIdx.x;
    if (e >= N_EDGES) return;
    int s = ei[e];
    int d = ei[N_EDGES + e];
    int p = atomicAdd(&fillpos[d], 1);
    csr_src[offs[d] + p] = s;
}

// ---- split fp32 -> (bf16 hi, bf16 lo) -------------------------------------
__global__ void k_split(const float* __restrict__ in, short* __restrict__ hi,
                        short* __restrict__ lo, int n4) {
    int i = blockIdx.x * blockDim.x + threadIdx.x;
    if (i >= n4) return;
    float4 v = ((const float4*)in)[i];
    unsigned short h0 = f2bf(v.x), h1 = f2bf(v.y), h2 = f2bf(v.z), h3 = f2bf(v.w);
    unsigned short l0 = f2bf(v.x - bf2f(h0)), l1 = f2bf(v.y - bf2f(h1));
    unsigned short l2 = f2bf(v.z - bf2f(h2)), l3 = f2bf(v.w - bf2f(h3));
    ushort4 vh; vh.x = h0; vh.y = h1; vh.z = h2; vh.w = h3;
    ushort4 vl; vl.x = l0; vl.y = l1; vl.z = l2; vl.w = l3;
    ((ushort4*)hi)[i] = vh;
    ((ushort4*)lo)[i] = vl;
}

// ---- W[128k x 128n] -> W^T splits: Wt[n][k] hi/lo --------------------------
__global__ void k_wsplit(const float* __restrict__ W, short* __restrict__ Wth,
                         short* __restrict__ Wtl) {
    int tid = blockIdx.x * blockDim.x + threadIdx.x;   // 16384
    int k = tid & 127, n = tid >> 7;
    float w = W[k * HID + n];
    unsigned short h = f2bf(w);
    Wth[n * HID + k] = (short)h;
    Wtl[n * HID + k] = (short)f2bf(w - bf2f(h));
}

// ---- MFMA GEMM: out[M x 128] = (A @ W) * scale[row] ------------------------
__global__ __launch_bounds__(256) void k_gemm_mfma(const short* __restrict__ Ah,
                                                   const short* __restrict__ Al,
                                                   const short* __restrict__ Wh,
                                                   const short* __restrict__ Wl,
                                                   float* __restrict__ out, int M,
                                                   const float* __restrict__ scale) {
    int wid  = threadIdx.x >> 6;
    int lane = threadIdx.x & 63;
    int row0 = blockIdx.x * 64 + wid * 16;
    int r    = lane & 15;
    int ko   = (lane >> 4) * 8;

    const short* Arh = Ah + (size_t)(row0 + r) * HID;
    const short* Arl = Al + (size_t)(row0 + r) * HID;
    short8 afh[4], afl[4];
    #pragma unroll
    for (int c = 0; c < 4; c++) {
        afh[c] = *(const short8*)(Arh + c * 32 + ko);
        afl[c] = *(const short8*)(Arl + c * 32 + ko);
    }

    f32x4 acc[8];
    #pragma unroll
    for (int n = 0; n < 8; n++) acc[n] = (f32x4){0.f, 0.f, 0.f, 0.f};

    #pragma unroll
    for (int n = 0; n < 8; n++) {
        const short* Wrh = Wh + (size_t)(n * 16 + r) * HID;
        const short* Wrl = Wl + (size_t)(n * 16 + r) * HID;
        #pragma unroll
        for (int c = 0; c < 4; c++) {
            short8 bh = *(const short8*)(Wrh + c * 32 + ko);
            short8 bl = *(const short8*)(Wrl + c * 32 + ko);
            acc[n] = __builtin_amdgcn_mfma_f32_16x16x32_bf16(afh[c], bh, acc[n], 0, 0, 0);
            acc[n] = __builtin_amdgcn_mfma_f32_16x16x32_bf16(afl[c], bh, acc[n], 0, 0, 0);
            acc[n] = __builtin_amdgcn_mfma_f32_16x16x32_bf16(afh[c], bl, acc[n], 0, 0, 0);
        }
    }

    int crow = row0 + (lane >> 4) * 4;
    #pragma unroll
    for (int q = 0; q < 4; q++) {
        int gr = crow + q;
        if (gr < M) {
            float s = scale[gr];
            #pragma unroll
            for (int n = 0; n < 8; n++)
                out[(size_t)gr * HID + n * 16 + (lane & 15)] = acc[n][q] * s;
        }
    }
}

// ---- GCN aggregation on pre-scaled features --------------------------------
// float4/lane, 32 lanes per row, 2 edge slots per wave.
// mode 1: relu + write bf16 split pair (hh,hl). mode 0: write fp32 hout, no relu.
__global__ __launch_bounds__(256) void k_agg(const float* __restrict__ tmpS,
                                             const int* __restrict__ offs,
                                             const int* __restrict__ csr_src,
                                             const float* __restrict__ dis,
                                             const float* __restrict__ bias,
                                             float* __restrict__ hout,
                                             short* __restrict__ hh,
                                             short* __restrict__ hl,
                                             int mode) {
    int node = blockIdx.x * 4 + (threadIdx.x >> 6);
    if (node >= N_NODES) return;
    int lane = threadIdx.x & 63;
    int c  = lane & 31;          // col group: floats [c*4, c*4+4)
    int e  = lane >> 5;          // edge slot 0/1
    int beg = offs[node], end = offs[node + 1];
    float dn = dis[node];

    float ax[4] = {}, ay[4] = {}, az[4] = {}, aw[4] = {};
    for (int j = beg; j < end; j += 8) {
        #pragma unroll
        for (int k = 0; k < 4; k++) {
            int jj = j + k * 2 + e;
            int jc = jj < end ? jj : end - 1;
            int s = csr_src[jc];
            float m = (jj < end) ? 1.0f : 0.0f;
            float4 v = *(const float4*)&tmpS[(size_t)s * HID + c * 4];
            ax[k] = fmaf(v.x, m, ax[k]);
            ay[k] = fmaf(v.y, m, ay[k]);
            az[k] = fmaf(v.z, m, az[k]);
            aw[k] = fmaf(v.w, m, aw[k]);
        }
    }
    float tx = (ax[0] + ax[1]) + (ax[2] + ax[3]);
    float ty = (ay[0] + ay[1]) + (ay[2] + ay[3]);
    float tz = (az[0] + az[1]) + (az[2] + az[3]);
    float tw = (aw[0] + aw[1]) + (aw[2] + aw[3]);
    // combine the two edge-slot halves (lane ^ 32)
    tx += __shfl_xor(tx, 32);
    ty += __shfl_xor(ty, 32);
    tz += __shfl_xor(tz, 32);
    tw += __shfl_xor(tw, 32);

    if (e == 0) {
        float4 self = *(const float4*)&tmpS[(size_t)node * HID + c * 4];
        float4 b4   = *(const float4*)&bias[c * 4];
        float ox = (tx + self.x) * dn + b4.x;
        float oy = (ty + self.y) * dn + b4.y;
        float oz = (tz + self.z) * dn + b4.z;
        float ow = (tw + self.w) * dn + b4.w;
        if (mode == 1) {
            ox = fmaxf(ox, 0.f); oy = fmaxf(oy, 0.f);
            oz = fmaxf(oz, 0.f); ow = fmaxf(ow, 0.f);
            unsigned short hx = f2bf(ox), hy = f2bf(oy), hz = f2bf(oz), hw = f2bf(ow);
            ushort4 vh; vh.x = hx; vh.y = hy; vh.z = hz; vh.w = hw;
            ushort4 vl;
            vl.x = f2bf(ox - bf2f(hx)); vl.y = f2bf(oy - bf2f(hy));
            vl.z = f2bf(oz - bf2f(hz)); vl.w = f2bf(ow - bf2f(hw));
            *(ushort4*)&hh[(size_t)node * HID + c * 4] = vh;
            *(ushort4*)&hl[(size_t)node * HID + c * 4] = vl;
        } else {
            float4 o = make_float4(ox, oy, oz, ow);
            *(float4*)&hout[(size_t)node * HID + c * 4] = o;
        }
    }
}

// ---- graph boundaries from sorted batch ------------------------------------
__global__ void k_bounds(const int* __restrict__ batch, int* __restrict__ gstart) {
    int n = blockIdx.x * blockDim.x + threadIdx.x;
    if (n >= N_NODES) return;
    int b  = batch[n];
    int bp = (n == 0) ? -1 : batch[n - 1];
    for (int g = bp + 1; g <= b; g++) gstart[g] = n;
    if (n == N_NODES - 1)
        for (int g = b + 1; g <= NUM_GRAPHS; g++) gstart[g] = N_NODES;
}

// ---- generalized-mean pool (p=2, sign preserving) + relu -------------------
__global__ __launch_bounds__(256) void k_pool(const float* __restrict__ h,
                                              const int* __restrict__ gstart,
                                              float* __restrict__ pooled) {
    int g = blockIdx.x * 4 + (threadIdx.x >> 6);
    if (g >= NUM_GRAPHS) return;
    int lane = threadIdx.x & 63;
    int beg = gstart[g], end = gstart[g + 1];
    float sx = 0.f, sy = 0.f;
    for (int n = beg; n < end; n++) {
        float2 v = *(const float2*)&h[n * HID + lane * 2];
        sx += signpow(v.x, false);
        sy += signpow(v.y, false);
    }
    float c  = fmaxf((float)(end - beg), 1.0f);
    float px = sx / c, py = sy / c;
    float rx = fmaxf(signpow(px, true), 0.f);
    float ry = fmaxf(signpow(py, true), 0.f);
    pooled[g * HID + lane * 2]     = rx;
    pooled[g * HID + lane * 2 + 1] = ry;
}

// ---- FF head ---------------------------------------------------------------
__global__ __launch_bounds__(128) void k_ff(const float* __restrict__ pooled,
                                            const float* __restrict__ Wf0,
                                            const float* __restrict__ bf0,
                                            const float* __restrict__ Wf1,
                                            const float* __restrict__ bf1,
                                            float* __restrict__ out) {
    __shared__ float row[128];
    __shared__ float zrow[128];
    int g = blockIdx.x, t = threadIdx.x;
    row[t] = pooled[g * HID + t];
    __syncthreads();
    float acc = bf0[t];
    #pragma unroll 8
    for (int k = 0; k < 128; k++) acc = fmaf(row[k], Wf0[k * 128 + t], acc);
    zrow[t] = fmaxf(acc, 0.f);
    __syncthreads();
    if (t < OUT_DIM) {
        float a2 = bf1[t];
        #pragma unroll 8
        for (int k = 0; k < 128; k++) a2 = fmaf(zrow[k], Wf1[k * OUT_DIM + t], a2);
        out[g * OUT_DIM + t] = a2;
    }
}

// ---------------------------------------------------------------------------
static inline size_t align256(size_t x) { return (x + 255) & ~(size_t)255; }

extern "C" void kernel_launch(void* const* d_in, const int* in_sizes, int n_in,
                              void* d_out, int out_size, void* d_ws, size_t ws_size,
                              hipStream_t stream) {
    const float* x     = (const float*)d_in[0];
    const int*   ei    = (const int*)d_in[1];
    const int*   batch = (const int*)d_in[2];
    const float* W0  = (const float*)d_in[3];  const float* b0  = (const float*)d_in[4];
    const float* W1  = (const float*)d_in[5];  const float* b1  = (const float*)d_in[6];
    const float* W2  = (const float*)d_in[7];  const float* b2  = (const float*)d_in[8];
    const float* Wf0 = (const float*)d_in[9];  const float* bf0 = (const float*)d_in[10];
    const float* Wf1 = (const float*)d_in[11]; const float* bf1 = (const float*)d_in[12];
    float* out = (float*)d_out;

    char* p = (char*)d_ws;
    float* tmp   = (float*)p; p += align256((size_t)M_PAD * HID * 4);
    short* bufAh = (short*)p; p += align256((size_t)M_PAD * HID * 2);
    short* bufAl = (short*)p; p += align256((size_t)M_PAD * HID * 2);
    short* bufBh = (short*)p; p += align256((size_t)M_PAD * HID * 2);
    short* bufBl = (short*)p; p += align256((size_t)M_PAD * HID * 2);
    float* h     = (float*)bufBh;   // aliases bufBh+bufBl, live only after layer2
    int*   cnt     = (int*)p;   p += align256((size_t)N_NODES * 4);
    int*   offs    = (int*)p;   p += align256((size_t)(N_NODES + 1) * 4);
    int*   fillpos = (int*)p;   p += align256((size_t)N_NODES * 4);
    int*   csr     = (int*)p;   p += align256((size_t)N_EDGES * 4);
    float* dis     = (float*)p; p += align256((size_t)N_NODES * 4);
    int*   gstart  = (int*)p;   p += align256((size_t)(NUM_GRAPHS + 1) * 4);
    float* pooled  = (float*)p; p += align256((size_t)NUM_GRAPHS * HID * 4);
    int*   bsum    = (int*)p;   p += align256((size_t)SCAN_NB * 4);
    int*   bbase   = (int*)p;   p += align256((size_t)SCAN_NB * 4);
    short* Wth0    = (short*)p; p += align256((size_t)HID * HID * 2);
    short* Wtl0    = (short*)p; p += align256((size_t)HID * HID * 2);
    short* Wth1    = (short*)p; p += align256((size_t)HID * HID * 2);
    short* Wtl1    = (short*)p; p += align256((size_t)HID * HID * 2);
    short* Wth2    = (short*)p; p += align256((size_t)HID * HID * 2);
    short* Wtl2    = (short*)p; p += align256((size_t)HID * HID * 2);

    hipMemsetAsync(cnt, 0, (size_t)N_NODES * 4, stream);
    hipMemsetAsync(fillpos, 0, (size_t)N_NODES * 4, stream);

    const int TB = 256;
    k_count<<<(N_EDGES + TB - 1) / TB, TB, 0, stream>>>(ei, cnt);
    k_scan_part <<<SCAN_NB, 256, 0, stream>>>(cnt, bsum);
    k_scan_base <<<1, 256, 0, stream>>>(bsum, bbase);
    k_scan_final<<<SCAN_NB, 256, 0, stream>>>(cnt, bbase, offs, dis);
    k_fill<<<(N_EDGES + TB - 1) / TB, TB, 0, stream>>>(ei, offs, fillpos, csr);

    // splits
    int n4 = N_NODES * HID / 4;
    k_split<<<(n4 + TB - 1) / TB, TB, 0, stream>>>(x, bufAh, bufAl, n4);
    k_wsplit<<<64, 256, 0, stream>>>(W0, Wth0, Wtl0);
    k_wsplit<<<64, 256, 0, stream>>>(W1, Wth1, Wtl1);
    k_wsplit<<<64, 256, 0, stream>>>(W2, Wth2, Wtl2);

    int gemm_blocks = M_PAD / 64;             // 782
    int agg_blocks  = (N_NODES + 3) / 4;

    // layer 0
    k_gemm_mfma<<<gemm_blocks, 256, 0, stream>>>(bufAh, bufAl, Wth0, Wtl0, tmp, N_NODES, dis);
    k_agg<<<agg_blocks, 256, 0, stream>>>(tmp, offs, csr, dis, b0, nullptr, bufBh, bufBl, 1);
    // layer 1
    k_gemm_mfma<<<gemm_blocks, 256, 0, stream>>>(bufBh, bufBl, Wth1, Wtl1, tmp, N_NODES, dis);
    k_agg<<<agg_blocks, 256, 0, stream>>>(tmp, offs, csr, dis, b1, nullptr, bufAh, bufAl, 1);
    // layer 2 (no relu, fp32 out for pooling)
    k_gemm_mfma<<<gemm_blocks, 256, 0, stream>>>(bufAh, bufAl, Wth2, Wtl2, tmp, N_NODES, dis);
    k_agg<<<agg_blocks, 256, 0, stream>>>(tmp, offs, csr, dis, b2, h, nullptr, nullptr, 0);

    k_bounds<<<(N_NODES + TB - 1) / TB, TB, 0, stream>>>(batch, gstart);
    k_pool<<<(NUM_GRAPHS + 3) / 4, 256, 0, stream>>>(h, gstart, pooled);
    k_ff<<<NUM_GRAPHS, 128, 0, stream>>>(pooled, Wf0, bf0, Wf1, bf1, out);
}

// Round 7
// 379.325 us; speedup vs baseline: 1.6893x; 1.1708x over previous
//
#include <hip/hip_runtime.h>

#define N_NODES   50000
#define M_PAD     50048            // 782 * 64
#define N_EDGES   800000
#define HID       128
#define OUT_DIM   64
#define NUM_GRAPHS 512
#define EPS       1e-6f
#define SCAN_NB   ((N_NODES + 255) / 256)   // 196

typedef __attribute__((ext_vector_type(8))) short short8;
typedef __attribute__((ext_vector_type(4))) float f32x4;

static __device__ __forceinline__ unsigned short f2bf(float f) {
    unsigned u = __builtin_bit_cast(unsigned, f);
    u += 0x7FFFu + ((u >> 16) & 1u);           // round-to-nearest-even
    return (unsigned short)(u >> 16);
}
static __device__ __forceinline__ float bf2f(unsigned short h) {
    unsigned u = ((unsigned)h) << 16;
    return __builtin_bit_cast(float, u);
}

static __device__ __forceinline__ float signpow(float x, bool sqrt_mode) {
    if (x == 0.0f) return 0.0f;
    float a = fabsf(x) + EPS;
    float v = sqrt_mode ? sqrtf(a) : a * a;
    return x > 0.0f ? v : -v;
}

// ---- CSR build ------------------------------------------------------------
__global__ void k_count(const int* __restrict__ ei, int* __restrict__ cnt) {
    int e = blockIdx.x * blockDim.x + threadIdx.x;
    if (e < N_EDGES) atomicAdd(&cnt[ei[N_EDGES + e]], 1);
}

__global__ __launch_bounds__(256) void k_scan_part(const int* __restrict__ cnt,
                                                   int* __restrict__ bsum) {
    __shared__ int sm[256];
    int t = threadIdx.x, i = blockIdx.x * 256 + t;
    sm[t] = (i < N_NODES) ? cnt[i] : 0;
    __syncthreads();
    for (int off = 128; off > 0; off >>= 1) {
        if (t < off) sm[t] += sm[t + off];
        __syncthreads();
    }
    if (t == 0) bsum[blockIdx.x] = sm[0];
}

__global__ __launch_bounds__(256) void k_scan_base(const int* __restrict__ bsum,
                                                   int* __restrict__ bbase) {
    __shared__ int sm[256];
    int t = threadIdx.x;
    int v = (t < SCAN_NB) ? bsum[t] : 0;
    sm[t] = v;
    __syncthreads();
    for (int off = 1; off < 256; off <<= 1) {
        int u = (t >= off) ? sm[t - off] : 0;
        __syncthreads();
        sm[t] += u;
        __syncthreads();
    }
    if (t < SCAN_NB) bbase[t] = sm[t] - v;   // exclusive
}

__global__ __launch_bounds__(256) void k_scan_final(const int* __restrict__ cnt,
                                                    const int* __restrict__ bbase,
                                                    int* __restrict__ offs,
                                                    float* __restrict__ dis) {
    __shared__ int sm[256];
    int t = threadIdx.x, i = blockIdx.x * 256 + t;
    int c = (i < N_NODES) ? cnt[i] : 0;
    sm[t] = c;
    __syncthreads();
    for (int off = 1; off < 256; off <<= 1) {
        int u = (t >= off) ? sm[t - off] : 0;
        __syncthreads();
        sm[t] += u;
        __syncthreads();
    }
    if (i < N_NODES) {
        offs[i] = bbase[blockIdx.x] + sm[t] - c;
        dis[i]  = rsqrtf((float)c + 1.0f);
    }
    if (blockIdx.x == 0 && t == 0) offs[N_NODES] = N_EDGES;
}

__global__ void k_fill(const int* __restrict__ ei, const int* __restrict__ offs,
                       int* __restrict__ fillpos, int* __restrict__ csr_src) {
    int e = blockIdx.x * blockDim.x + threadIdx.x;
    if (e >= N_EDGES) return;
    int s = ei[e];
    int d = ei[N_EDGES + e];
    int p = atomicAdd(&fillpos[d], 1);
    csr_src[offs[d] + p] = s;
}

// ---- split fp32 -> (bf16 hi, bf16 lo) -------------------------------------
__global__ void k_split(const float* __restrict__ in, short* __restrict__ hi,
                        short* __restrict__ lo, int n4) {
    int i = blockIdx.x * blockDim.x + threadIdx.x;
    if (i >= n4) return;
    float4 v = ((const float4*)in)[i];
    unsigned short h0 = f2bf(v.x), h1 = f2bf(v.y), h2 = f2bf(v.z), h3 = f2bf(v.w);
    unsigned short l0 = f2bf(v.x - bf2f(h0)), l1 = f2bf(v.y - bf2f(h1));
    unsigned short l2 = f2bf(v.z - bf2f(h2)), l3 = f2bf(v.w - bf2f(h3));
    ushort4 vh; vh.x = h0; vh.y = h1; vh.z = h2; vh.w = h3;
    ushort4 vl; vl.x = l0; vl.y = l1; vl.z = l2; vl.w = l3;
    ((ushort4*)hi)[i] = vh;
    ((ushort4*)lo)[i] = vl;
}

// ---- all three W[128k x 128n] -> W^T splits [3][128n][128k] hi/lo ----------
__global__ void k_wsplit3(const float* __restrict__ W0, const float* __restrict__ W1,
                          const float* __restrict__ W2, short* __restrict__ Wth,
                          short* __restrict__ Wtl) {
    int which = blockIdx.y;
    const float* W = which == 0 ? W0 : (which == 1 ? W1 : W2);
    int tid = blockIdx.x * blockDim.x + threadIdx.x;   // 16384
    int k = tid & 127, n = tid >> 7;
    float w = W[k * HID + n];
    unsigned short h = f2bf(w);
    Wth[which * HID * HID + n * HID + k] = (short)h;
    Wtl[which * HID * HID + n * HID + k] = (short)f2bf(w - bf2f(h));
}

// ---- MFMA GEMM: (A @ W) * scale[row] -> bf16 hi/lo pair --------------------
__global__ __launch_bounds__(256) void k_gemm_mfma(const short* __restrict__ Ah,
                                                   const short* __restrict__ Al,
                                                   const short* __restrict__ Wh,
                                                   const short* __restrict__ Wl,
                                                   unsigned short* __restrict__ th,
                                                   unsigned short* __restrict__ tl,
                                                   int M,
                                                   const float* __restrict__ scale) {
    int wid  = threadIdx.x >> 6;
    int lane = threadIdx.x & 63;
    int row0 = blockIdx.x * 64 + wid * 16;
    int r    = lane & 15;
    int ko   = (lane >> 4) * 8;

    const short* Arh = Ah + (size_t)(row0 + r) * HID;
    const short* Arl = Al + (size_t)(row0 + r) * HID;
    short8 afh[4], afl[4];
    #pragma unroll
    for (int c = 0; c < 4; c++) {
        afh[c] = *(const short8*)(Arh + c * 32 + ko);
        afl[c] = *(const short8*)(Arl + c * 32 + ko);
    }

    f32x4 acc[8];
    #pragma unroll
    for (int n = 0; n < 8; n++) acc[n] = (f32x4){0.f, 0.f, 0.f, 0.f};

    #pragma unroll
    for (int n = 0; n < 8; n++) {
        const short* Wrh = Wh + (size_t)(n * 16 + r) * HID;
        const short* Wrl = Wl + (size_t)(n * 16 + r) * HID;
        #pragma unroll
        for (int c = 0; c < 4; c++) {
            short8 bh = *(const short8*)(Wrh + c * 32 + ko);
            short8 bl = *(const short8*)(Wrl + c * 32 + ko);
            acc[n] = __builtin_amdgcn_mfma_f32_16x16x32_bf16(afh[c], bh, acc[n], 0, 0, 0);
            acc[n] = __builtin_amdgcn_mfma_f32_16x16x32_bf16(afl[c], bh, acc[n], 0, 0, 0);
            acc[n] = __builtin_amdgcn_mfma_f32_16x16x32_bf16(afh[c], bl, acc[n], 0, 0, 0);
        }
    }

    int crow = row0 + (lane >> 4) * 4;
    #pragma unroll
    for (int q = 0; q < 4; q++) {
        int gr = crow + q;
        if (gr < M) {
            float s = scale[gr];
            #pragma unroll
            for (int n = 0; n < 8; n++) {
                float v = acc[n][q] * s;
                unsigned short hi = f2bf(v);
                unsigned short lo = f2bf(v - bf2f(hi));
                th[(size_t)gr * HID + n * 16 + (lane & 15)] = hi;
                tl[(size_t)gr * HID + n * 16 + (lane & 15)] = lo;
            }
        }
    }
}

// ---- GCN aggregation: gather bf16-hi rows; self term = hi+lo (exact) -------
// mode 1: relu + write bf16 split pair (hh,hl). mode 0: write fp32 hout, no relu.
__global__ __launch_bounds__(256) void k_agg(const unsigned short* __restrict__ th,
                                             const unsigned short* __restrict__ tl,
                                             const int* __restrict__ offs,
                                             const int* __restrict__ csr_src,
                                             const float* __restrict__ dis,
                                             const float* __restrict__ bias,
                                             float* __restrict__ hout,
                                             short* __restrict__ hh,
                                             short* __restrict__ hl,
                                             int mode) {
    int node = blockIdx.x * 4 + (threadIdx.x >> 6);
    if (node >= N_NODES) return;
    int lane = threadIdx.x & 63;
    int c  = lane & 31;          // col group: cols [c*4, c*4+4)
    int e  = lane >> 5;          // edge slot 0/1
    int beg = offs[node], end = offs[node + 1];
    float dn = dis[node];

    float ax[4] = {}, ay[4] = {}, az[4] = {}, aw[4] = {};
    for (int j = beg; j < end; j += 8) {
        #pragma unroll
        for (int k = 0; k < 4; k++) {
            int jj = j + k * 2 + e;
            int jc = jj < end ? jj : end - 1;
            int s = csr_src[jc];
            float m = (jj < end) ? 1.0f : 0.0f;
            // 4 bf16 cols = 2 dwords; hi-half extract is free-form bit ops
            uint2 v = *(const uint2*)&th[(size_t)s * HID + c * 4];
            float v0 = __builtin_bit_cast(float, v.x << 16);
            float v1 = __builtin_bit_cast(float, v.x & 0xFFFF0000u);
            float v2 = __builtin_bit_cast(float, v.y << 16);
            float v3 = __builtin_bit_cast(float, v.y & 0xFFFF0000u);
            ax[k] = fmaf(v0, m, ax[k]);
            ay[k] = fmaf(v1, m, ay[k]);
            az[k] = fmaf(v2, m, az[k]);
            aw[k] = fmaf(v3, m, aw[k]);
        }
    }
    float tx = (ax[0] + ax[1]) + (ax[2] + ax[3]);
    float ty = (ay[0] + ay[1]) + (ay[2] + ay[3]);
    float tz = (az[0] + az[1]) + (az[2] + az[3]);
    float tw = (aw[0] + aw[1]) + (aw[2] + aw[3]);
    tx += __shfl_xor(tx, 32);
    ty += __shfl_xor(ty, 32);
    tz += __shfl_xor(tz, 32);
    tw += __shfl_xor(tw, 32);

    if (e == 0) {
        ushort4 sh = *(const ushort4*)&th[(size_t)node * HID + c * 4];
        ushort4 sl = *(const ushort4*)&tl[(size_t)node * HID + c * 4];
        float4 b4  = *(const float4*)&bias[c * 4];
        float ox = (tx + bf2f(sh.x) + bf2f(sl.x)) * dn + b4.x;
        float oy = (ty + bf2f(sh.y) + bf2f(sl.y)) * dn + b4.y;
        float oz = (tz + bf2f(sh.z) + bf2f(sl.z)) * dn + b4.z;
        float ow = (tw + bf2f(sh.w) + bf2f(sl.w)) * dn + b4.w;
        if (mode == 1) {
            ox = fmaxf(ox, 0.f); oy = fmaxf(oy, 0.f);
            oz = fmaxf(oz, 0.f); ow = fmaxf(ow, 0.f);
            unsigned short hx = f2bf(ox), hy = f2bf(oy), hz = f2bf(oz), hw = f2bf(ow);
            ushort4 vh; vh.x = hx; vh.y = hy; vh.z = hz; vh.w = hw;
            ushort4 vl;
            vl.x = f2bf(ox - bf2f(hx)); vl.y = f2bf(oy - bf2f(hy));
            vl.z = f2bf(oz - bf2f(hz)); vl.w = f2bf(ow - bf2f(hw));
            *(ushort4*)&hh[(size_t)node * HID + c * 4] = vh;
            *(ushort4*)&hl[(size_t)node * HID + c * 4] = vl;
        } else {
            float4 o = make_float4(ox, oy, oz, ow);
            *(float4*)&hout[(size_t)node * HID + c * 4] = o;
        }
    }
}

// ---- graph boundaries from sorted batch ------------------------------------
__global__ void k_bounds(const int* __restrict__ batch, int* __restrict__ gstart) {
    int n = blockIdx.x * blockDim.x + threadIdx.x;
    if (n >= N_NODES) return;
    int b  = batch[n];
    int bp = (n == 0) ? -1 : batch[n - 1];
    for (int g = bp + 1; g <= b; g++) gstart[g] = n;
    if (n == N_NODES - 1)
        for (int g = b + 1; g <= NUM_GRAPHS; g++) gstart[g] = N_NODES;
}

// ---- generalized-mean pool (p=2, sign preserving) + relu -------------------
__global__ __launch_bounds__(256) void k_pool(const float* __restrict__ h,
                                              const int* __restrict__ gstart,
                                              float* __restrict__ pooled) {
    int g = blockIdx.x * 4 + (threadIdx.x >> 6);
    if (g >= NUM_GRAPHS) return;
    int lane = threadIdx.x & 63;
    int beg = gstart[g], end = gstart[g + 1];
    float sx = 0.f, sy = 0.f;
    for (int n = beg; n < end; n++) {
        float2 v = *(const float2*)&h[n * HID + lane * 2];
        sx += signpow(v.x, false);
        sy += signpow(v.y, false);
    }
    float c  = fmaxf((float)(end - beg), 1.0f);
    float px = sx / c, py = sy / c;
    float rx = fmaxf(signpow(px, true), 0.f);
    float ry = fmaxf(signpow(py, true), 0.f);
    pooled[g * HID + lane * 2]     = rx;
    pooled[g * HID + lane * 2 + 1] = ry;
}

// ---- FF head ---------------------------------------------------------------
__global__ __launch_bounds__(128) void k_ff(const float* __restrict__ pooled,
                                            const float* __restrict__ Wf0,
                                            const float* __restrict__ bf0,
                                            const float* __restrict__ Wf1,
                                            const float* __restrict__ bf1,
                                            float* __restrict__ out) {
    __shared__ float row[128];
    __shared__ float zrow[128];
    int g = blockIdx.x, t = threadIdx.x;
    row[t] = pooled[g * HID + t];
    __syncthreads();
    float acc = bf0[t];
    #pragma unroll 8
    for (int k = 0; k < 128; k++) acc = fmaf(row[k], Wf0[k * 128 + t], acc);
    zrow[t] = fmaxf(acc, 0.f);
    __syncthreads();
    if (t < OUT_DIM) {
        float a2 = bf1[t];
        #pragma unroll 8
        for (int k = 0; k < 128; k++) a2 = fmaf(zrow[k], Wf1[k * OUT_DIM + t], a2);
        out[g * OUT_DIM + t] = a2;
    }
}

// ---------------------------------------------------------------------------
static inline size_t align256(size_t x) { return (x + 255) & ~(size_t)255; }

extern "C" void kernel_launch(void* const* d_in, const int* in_sizes, int n_in,
                              void* d_out, int out_size, void* d_ws, size_t ws_size,
                              hipStream_t stream) {
    const float* x     = (const float*)d_in[0];
    const int*   ei    = (const int*)d_in[1];
    const int*   batch = (const int*)d_in[2];
    const float* W0  = (const float*)d_in[3];  const float* b0  = (const float*)d_in[4];
    const float* W1  = (const float*)d_in[5];  const float* b1  = (const float*)d_in[6];
    const float* W2  = (const float*)d_in[7];  const float* b2  = (const float*)d_in[8];
    const float* Wf0 = (const float*)d_in[9];  const float* bf0 = (const float*)d_in[10];
    const float* Wf1 = (const float*)d_in[11]; const float* bf1 = (const float*)d_in[12];
    float* out = (float*)d_out;

    char* p = (char*)d_ws;
    unsigned short* th = (unsigned short*)p; p += align256((size_t)M_PAD * HID * 2);
    unsigned short* tl = (unsigned short*)p; p += align256((size_t)M_PAD * HID * 2);
    short* bufAh = (short*)p; p += align256((size_t)M_PAD * HID * 2);
    short* bufAl = (short*)p; p += align256((size_t)M_PAD * HID * 2);
    short* bufBh = (short*)p; p += align256((size_t)M_PAD * HID * 2);
    short* bufBl = (short*)p; p += align256((size_t)M_PAD * HID * 2);
    float* h     = (float*)bufBh;   // aliases bufBh+bufBl (contiguous), live only after layer2
    int*   cnt     = (int*)p;   p += align256((size_t)N_NODES * 4);
    int*   offs    = (int*)p;   p += align256((size_t)(N_NODES + 1) * 4);
    int*   fillpos = (int*)p;   p += align256((size_t)N_NODES * 4);
    int*   csr     = (int*)p;   p += align256((size_t)N_EDGES * 4);
    float* dis     = (float*)p; p += align256((size_t)N_NODES * 4);
    int*   gstart  = (int*)p;   p += align256((size_t)(NUM_GRAPHS + 1) * 4);
    float* pooled  = (float*)p; p += align256((size_t)NUM_GRAPHS * HID * 4);
    int*   bsum    = (int*)p;   p += align256((size_t)SCAN_NB * 4);
    int*   bbase   = (int*)p;   p += align256((size_t)SCAN_NB * 4);
    short* Wth     = (short*)p; p += align256((size_t)3 * HID * HID * 2);
    short* Wtl     = (short*)p; p += align256((size_t)3 * HID * HID * 2);

    hipMemsetAsync(cnt, 0, (size_t)N_NODES * 4, stream);
    hipMemsetAsync(fillpos, 0, (size_t)N_NODES * 4, stream);

    const int TB = 256;
    k_count<<<(N_EDGES + TB - 1) / TB, TB, 0, stream>>>(ei, cnt);
    k_scan_part <<<SCAN_NB, 256, 0, stream>>>(cnt, bsum);
    k_scan_base <<<1, 256, 0, stream>>>(bsum, bbase);
    k_scan_final<<<SCAN_NB, 256, 0, stream>>>(cnt, bbase, offs, dis);
    k_fill<<<(N_EDGES + TB - 1) / TB, TB, 0, stream>>>(ei, offs, fillpos, csr);

    // splits
    int n4 = N_NODES * HID / 4;
    k_split<<<(n4 + TB - 1) / TB, TB, 0, stream>>>(x, bufAh, bufAl, n4);
    dim3 wg(64, 3);
    k_wsplit3<<<wg, 256, 0, stream>>>(W0, W1, W2, Wth, Wtl);

    int gemm_blocks = M_PAD / 64;             // 782
    int agg_blocks  = (N_NODES + 3) / 4;

    // layer 0
    k_gemm_mfma<<<gemm_blocks, 256, 0, stream>>>(bufAh, bufAl, Wth, Wtl,
                                                 th, tl, N_NODES, dis);
    k_agg<<<agg_blocks, 256, 0, stream>>>(th, tl, offs, csr, dis, b0,
                                          nullptr, bufBh, bufBl, 1);
    // layer 1
    k_gemm_mfma<<<gemm_blocks, 256, 0, stream>>>(bufBh, bufBl, Wth + HID * HID, Wtl + HID * HID,
                                                 th, tl, N_NODES, dis);
    k_agg<<<agg_blocks, 256, 0, stream>>>(th, tl, offs, csr, dis, b1,
                                          nullptr, bufAh, bufAl, 1);
    // layer 2 (no relu, fp32 out for pooling)
    k_gemm_mfma<<<gemm_blocks, 256, 0, stream>>>(bufAh, bufAl, Wth + 2 * HID * HID, Wtl + 2 * HID * HID,
                                                 th, tl, N_NODES, dis);
    k_agg<<<agg_blocks, 256, 0, stream>>>(th, tl, offs, csr, dis, b2,
                                          h, nullptr, nullptr, 0);

    k_bounds<<<(N_NODES + TB - 1) / TB, TB, 0, stream>>>(batch, gstart);
    k_pool<<<(NUM_GRAPHS + 3) / 4, 256, 0, stream>>>(h, gstart, pooled);
    k_ff<<<NUM_GRAPHS, 128, 0, stream>>>(pooled, Wf0, bf0, Wf1, bf1, out);
}

// Round 8
// 348.592 us; speedup vs baseline: 1.8383x; 1.0882x over previous
//
#include <hip/hip_runtime.h>

#define N_NODES   50000
#define M_PAD     50048            // 782 * 64
#define N_EDGES   800000
#define HID       128
#define OUT_DIM   64
#define NUM_GRAPHS 512
#define EPS       1e-6f
#define SCAN_NB   ((N_NODES + 255) / 256)   // 196

typedef __attribute__((ext_vector_type(8))) short short8;
typedef __attribute__((ext_vector_type(4))) float f32x4;

static __device__ __forceinline__ unsigned short f2bf(float f) {
    unsigned u = __builtin_bit_cast(unsigned, f);
    u += 0x7FFFu + ((u >> 16) & 1u);           // round-to-nearest-even
    return (unsigned short)(u >> 16);
}
static __device__ __forceinline__ float bf2f(unsigned short h) {
    unsigned u = ((unsigned)h) << 16;
    return __builtin_bit_cast(float, u);
}

static __device__ __forceinline__ float signpow(float x, bool sqrt_mode) {
    if (x == 0.0f) return 0.0f;
    float a = fabsf(x) + EPS;
    float v = sqrt_mode ? sqrtf(a) : a * a;
    return x > 0.0f ? v : -v;
}

// ---- CSR build ------------------------------------------------------------
__global__ void k_count(const int* __restrict__ ei, int* __restrict__ cnt) {
    int e = blockIdx.x * blockDim.x + threadIdx.x;
    if (e < N_EDGES) atomicAdd(&cnt[ei[N_EDGES + e]], 1);
}

__global__ __launch_bounds__(256) void k_scan_part(const int* __restrict__ cnt,
                                                   int* __restrict__ bsum) {
    __shared__ int sm[256];
    int t = threadIdx.x, i = blockIdx.x * 256 + t;
    sm[t] = (i < N_NODES) ? cnt[i] : 0;
    __syncthreads();
    for (int off = 128; off > 0; off >>= 1) {
        if (t < off) sm[t] += sm[t + off];
        __syncthreads();
    }
    if (t == 0) bsum[blockIdx.x] = sm[0];
}

__global__ __launch_bounds__(256) void k_scan_base(const int* __restrict__ bsum,
                                                   int* __restrict__ bbase) {
    __shared__ int sm[256];
    int t = threadIdx.x;
    int v = (t < SCAN_NB) ? bsum[t] : 0;
    sm[t] = v;
    __syncthreads();
    for (int off = 1; off < 256; off <<= 1) {
        int u = (t >= off) ? sm[t - off] : 0;
        __syncthreads();
        sm[t] += u;
        __syncthreads();
    }
    if (t < SCAN_NB) bbase[t] = sm[t] - v;   // exclusive
}

__global__ __launch_bounds__(256) void k_scan_final(const int* __restrict__ cnt,
                                                    const int* __restrict__ bbase,
                                                    int* __restrict__ offs,
                                                    float* __restrict__ dis) {
    __shared__ int sm[256];
    int t = threadIdx.x, i = blockIdx.x * 256 + t;
    int c = (i < N_NODES) ? cnt[i] : 0;
    sm[t] = c;
    __syncthreads();
    for (int off = 1; off < 256; off <<= 1) {
        int u = (t >= off) ? sm[t - off] : 0;
        __syncthreads();
        sm[t] += u;
        __syncthreads();
    }
    if (i < N_NODES) {
        offs[i] = bbase[blockIdx.x] + sm[t] - c;
        dis[i]  = rsqrtf((float)c + 1.0f);
    }
    if (blockIdx.x == 0 && t == 0) offs[N_NODES] = N_EDGES;
}

__global__ void k_fill(const int* __restrict__ ei, const int* __restrict__ offs,
                       int* __restrict__ fillpos, int* __restrict__ csr_src) {
    int e = blockIdx.x * blockDim.x + threadIdx.x;
    if (e >= N_EDGES) return;
    int s = ei[e];
    int d = ei[N_EDGES + e];
    int p = atomicAdd(&fillpos[d], 1);
    csr_src[offs[d] + p] = s;
}

// ---- split fp32 -> (bf16 hi, bf16 lo) -------------------------------------
__global__ void k_split(const float* __restrict__ in, short* __restrict__ hi,
                        short* __restrict__ lo, int n4) {
    int i = blockIdx.x * blockDim.x + threadIdx.x;
    if (i >= n4) return;
    float4 v = ((const float4*)in)[i];
    unsigned short h0 = f2bf(v.x), h1 = f2bf(v.y), h2 = f2bf(v.z), h3 = f2bf(v.w);
    unsigned short l0 = f2bf(v.x - bf2f(h0)), l1 = f2bf(v.y - bf2f(h1));
    unsigned short l2 = f2bf(v.z - bf2f(h2)), l3 = f2bf(v.w - bf2f(h3));
    ushort4 vh; vh.x = h0; vh.y = h1; vh.z = h2; vh.w = h3;
    ushort4 vl; vl.x = l0; vl.y = l1; vl.z = l2; vl.w = l3;
    ((ushort4*)hi)[i] = vh;
    ((ushort4*)lo)[i] = vl;
}

// ---- all three W[128k x 128n] -> W^T splits [3][128n][128k] hi/lo ----------
__global__ void k_wsplit3(const float* __restrict__ W0, const float* __restrict__ W1,
                          const float* __restrict__ W2, short* __restrict__ Wth,
                          short* __restrict__ Wtl) {
    int which = blockIdx.y;
    const float* W = which == 0 ? W0 : (which == 1 ? W1 : W2);
    int tid = blockIdx.x * blockDim.x + threadIdx.x;   // 16384
    int k = tid & 127, n = tid >> 7;
    float w = W[k * HID + n];
    unsigned short h = f2bf(w);
    Wth[which * HID * HID + n * HID + k] = (short)h;
    Wtl[which * HID * HID + n * HID + k] = (short)f2bf(w - bf2f(h));
}

// ---- MFMA GEMM: (A @ W) * scale[row] -> bf16 hi/lo pair --------------------
__global__ __launch_bounds__(256) void k_gemm_mfma(const short* __restrict__ Ah,
                                                   const short* __restrict__ Al,
                                                   const short* __restrict__ Wh,
                                                   const short* __restrict__ Wl,
                                                   unsigned short* __restrict__ th,
                                                   unsigned short* __restrict__ tl,
                                                   int M,
                                                   const float* __restrict__ scale) {
    int wid  = threadIdx.x >> 6;
    int lane = threadIdx.x & 63;
    int row0 = blockIdx.x * 64 + wid * 16;
    int r    = lane & 15;
    int ko   = (lane >> 4) * 8;

    const short* Arh = Ah + (size_t)(row0 + r) * HID;
    const short* Arl = Al + (size_t)(row0 + r) * HID;
    short8 afh[4], afl[4];
    #pragma unroll
    for (int c = 0; c < 4; c++) {
        afh[c] = *(const short8*)(Arh + c * 32 + ko);
        afl[c] = *(const short8*)(Arl + c * 32 + ko);
    }

    f32x4 acc[8];
    #pragma unroll
    for (int n = 0; n < 8; n++) acc[n] = (f32x4){0.f, 0.f, 0.f, 0.f};

    #pragma unroll
    for (int n = 0; n < 8; n++) {
        const short* Wrh = Wh + (size_t)(n * 16 + r) * HID;
        const short* Wrl = Wl + (size_t)(n * 16 + r) * HID;
        #pragma unroll
        for (int c = 0; c < 4; c++) {
            short8 bh = *(const short8*)(Wrh + c * 32 + ko);
            short8 bl = *(const short8*)(Wrl + c * 32 + ko);
            acc[n] = __builtin_amdgcn_mfma_f32_16x16x32_bf16(afh[c], bh, acc[n], 0, 0, 0);
            acc[n] = __builtin_amdgcn_mfma_f32_16x16x32_bf16(afl[c], bh, acc[n], 0, 0, 0);
            acc[n] = __builtin_amdgcn_mfma_f32_16x16x32_bf16(afh[c], bl, acc[n], 0, 0, 0);
        }
    }

    int crow = row0 + (lane >> 4) * 4;
    #pragma unroll
    for (int q = 0; q < 4; q++) {
        int gr = crow + q;
        if (gr < M) {
            float s = scale[gr];
            #pragma unroll
            for (int n = 0; n < 8; n++) {
                float v = acc[n][q] * s;
                unsigned short hi = f2bf(v);
                unsigned short lo = f2bf(v - bf2f(hi));
                th[(size_t)gr * HID + n * 16 + (lane & 15)] = hi;
                tl[(size_t)gr * HID + n * 16 + (lane & 15)] = lo;
            }
        }
    }
}

// ---- GCN aggregation: gather bf16-hi rows; self term = hi+lo (exact) -------
__global__ __launch_bounds__(256) void k_agg(const unsigned short* __restrict__ th,
                                             const unsigned short* __restrict__ tl,
                                             const int* __restrict__ offs,
                                             const int* __restrict__ csr_src,
                                             const float* __restrict__ dis,
                                             const float* __restrict__ bias,
                                             float* __restrict__ hout,
                                             short* __restrict__ hh,
                                             short* __restrict__ hl,
                                             int mode) {
    int node = blockIdx.x * 4 + (threadIdx.x >> 6);
    if (node >= N_NODES) return;
    int lane = threadIdx.x & 63;
    int c  = lane & 31;          // col group: cols [c*4, c*4+4)
    int e  = lane >> 5;          // edge slot 0/1
    int beg = offs[node], end = offs[node + 1];
    float dn = dis[node];

    float ax[4] = {}, ay[4] = {}, az[4] = {}, aw[4] = {};
    for (int j = beg; j < end; j += 8) {
        #pragma unroll
        for (int k = 0; k < 4; k++) {
            int jj = j + k * 2 + e;
            int jc = jj < end ? jj : end - 1;
            int s = csr_src[jc];
            float m = (jj < end) ? 1.0f : 0.0f;
            uint2 v = *(const uint2*)&th[(size_t)s * HID + c * 4];
            float v0 = __builtin_bit_cast(float, v.x << 16);
            float v1 = __builtin_bit_cast(float, v.x & 0xFFFF0000u);
            float v2 = __builtin_bit_cast(float, v.y << 16);
            float v3 = __builtin_bit_cast(float, v.y & 0xFFFF0000u);
            ax[k] = fmaf(v0, m, ax[k]);
            ay[k] = fmaf(v1, m, ay[k]);
            az[k] = fmaf(v2, m, az[k]);
            aw[k] = fmaf(v3, m, aw[k]);
        }
    }
    float tx = (ax[0] + ax[1]) + (ax[2] + ax[3]);
    float ty = (ay[0] + ay[1]) + (ay[2] + ay[3]);
    float tz = (az[0] + az[1]) + (az[2] + az[3]);
    float tw = (aw[0] + aw[1]) + (aw[2] + aw[3]);
    tx += __shfl_xor(tx, 32);
    ty += __shfl_xor(ty, 32);
    tz += __shfl_xor(tz, 32);
    tw += __shfl_xor(tw, 32);

    if (e == 0) {
        ushort4 sh = *(const ushort4*)&th[(size_t)node * HID + c * 4];
        ushort4 sl = *(const ushort4*)&tl[(size_t)node * HID + c * 4];
        float4 b4  = *(const float4*)&bias[c * 4];
        float ox = (tx + bf2f(sh.x) + bf2f(sl.x)) * dn + b4.x;
        float oy = (ty + bf2f(sh.y) + bf2f(sl.y)) * dn + b4.y;
        float oz = (tz + bf2f(sh.z) + bf2f(sl.z)) * dn + b4.z;
        float ow = (tw + bf2f(sh.w) + bf2f(sl.w)) * dn + b4.w;
        if (mode == 1) {
            ox = fmaxf(ox, 0.f); oy = fmaxf(oy, 0.f);
            oz = fmaxf(oz, 0.f); ow = fmaxf(ow, 0.f);
            unsigned short hx = f2bf(ox), hy = f2bf(oy), hz = f2bf(oz), hw = f2bf(ow);
            ushort4 vh; vh.x = hx; vh.y = hy; vh.z = hz; vh.w = hw;
            ushort4 vl;
            vl.x = f2bf(ox - bf2f(hx)); vl.y = f2bf(oy - bf2f(hy));
            vl.z = f2bf(oz - bf2f(hz)); vl.w = f2bf(ow - bf2f(hw));
            *(ushort4*)&hh[(size_t)node * HID + c * 4] = vh;
            *(ushort4*)&hl[(size_t)node * HID + c * 4] = vl;
        } else {
            float4 o = make_float4(ox, oy, oz, ow);
            *(float4*)&hout[(size_t)node * HID + c * 4] = o;
        }
    }
}

// ---- graph boundaries from sorted batch ------------------------------------
__global__ void k_bounds(const int* __restrict__ batch, int* __restrict__ gstart) {
    int n = blockIdx.x * blockDim.x + threadIdx.x;
    if (n >= N_NODES) return;
    int b  = batch[n];
    int bp = (n == 0) ? -1 : batch[n - 1];
    for (int g = bp + 1; g <= b; g++) gstart[g] = n;
    if (n == N_NODES - 1)
        for (int g = b + 1; g <= NUM_GRAPHS; g++) gstart[g] = N_NODES;
}

// ---- generalized-mean pool: one block (256t) per graph ----------------------
// threads = 4 node-slots x 64 col-groups (float2 each)
__global__ __launch_bounds__(256) void k_pool(const float* __restrict__ h,
                                              const int* __restrict__ gstart,
                                              float* __restrict__ pooled) {
    __shared__ float smx[4][64], smy[4][64];
    int g = blockIdx.x;
    int t = threadIdx.x;
    int c = t & 63;          // col group (2 floats)
    int slot = t >> 6;       // 0..3
    int beg = gstart[g], end = gstart[g + 1];

    float sx = 0.f, sy = 0.f;
    for (int n = beg + slot; n < end; n += 4) {
        float2 v = *(const float2*)&h[(size_t)n * HID + c * 2];
        sx += signpow(v.x, false);
        sy += signpow(v.y, false);
    }
    smx[slot][c] = sx; smy[slot][c] = sy;
    __syncthreads();
    if (slot == 0) {
        sx = (smx[0][c] + smx[1][c]) + (smx[2][c] + smx[3][c]);
        sy = (smy[0][c] + smy[1][c]) + (smy[2][c] + smy[3][c]);
        float cnt = fmaxf((float)(end - beg), 1.0f);
        float px = sx / cnt, py = sy / cnt;
        pooled[g * HID + c * 2]     = fmaxf(signpow(px, true), 0.f);
        pooled[g * HID + c * 2 + 1] = fmaxf(signpow(py, true), 0.f);
    }
}

// ---- FF head ---------------------------------------------------------------
__global__ __launch_bounds__(128) void k_ff(const float* __restrict__ pooled,
                                            const float* __restrict__ Wf0,
                                            const float* __restrict__ bf0,
                                            const float* __restrict__ Wf1,
                                            const float* __restrict__ bf1,
                                            float* __restrict__ out) {
    __shared__ float row[128];
    __shared__ float zrow[128];
    int g = blockIdx.x, t = threadIdx.x;
    row[t] = pooled[g * HID + t];
    __syncthreads();
    float acc = bf0[t];
    #pragma unroll 8
    for (int k = 0; k < 128; k++) acc = fmaf(row[k], Wf0[k * 128 + t], acc);
    zrow[t] = fmaxf(acc, 0.f);
    __syncthreads();
    if (t < OUT_DIM) {
        float a2 = bf1[t];
        #pragma unroll 8
        for (int k = 0; k < 128; k++) a2 = fmaf(zrow[k], Wf1[k * OUT_DIM + t], a2);
        out[g * OUT_DIM + t] = a2;
    }
}

// ---------------------------------------------------------------------------
static inline size_t align256(size_t x) { return (x + 255) & ~(size_t)255; }

extern "C" void kernel_launch(void* const* d_in, const int* in_sizes, int n_in,
                              void* d_out, int out_size, void* d_ws, size_t ws_size,
                              hipStream_t stream) {
    const float* x     = (const float*)d_in[0];
    const int*   ei    = (const int*)d_in[1];
    const int*   batch = (const int*)d_in[2];
    const float* W0  = (const float*)d_in[3];  const float* b0  = (const float*)d_in[4];
    const float* W1  = (const float*)d_in[5];  const float* b1  = (const float*)d_in[6];
    const float* W2  = (const float*)d_in[7];  const float* b2  = (const float*)d_in[8];
    const float* Wf0 = (const float*)d_in[9];  const float* bf0 = (const float*)d_in[10];
    const float* Wf1 = (const float*)d_in[11]; const float* bf1 = (const float*)d_in[12];
    float* out = (float*)d_out;

    char* p = (char*)d_ws;
    unsigned short* th = (unsigned short*)p; p += align256((size_t)M_PAD * HID * 2);
    unsigned short* tl = (unsigned short*)p; p += align256((size_t)M_PAD * HID * 2);
    short* bufAh = (short*)p; p += align256((size_t)M_PAD * HID * 2);
    short* bufAl = (short*)p; p += align256((size_t)M_PAD * HID * 2);
    short* bufBh = (short*)p; p += align256((size_t)M_PAD * HID * 2);
    short* bufBl = (short*)p; p += align256((size_t)M_PAD * HID * 2);
    float* h     = (float*)bufBh;   // aliases bufBh+bufBl (contiguous), live only after layer2
    int*   cnt     = (int*)p;   p += align256((size_t)N_NODES * 4);
    int*   offs    = (int*)p;   p += align256((size_t)(N_NODES + 1) * 4);
    int*   fillpos = (int*)p;   p += align256((size_t)N_NODES * 4);
    int*   csr     = (int*)p;   p += align256((size_t)N_EDGES * 4);
    float* dis     = (float*)p; p += align256((size_t)N_NODES * 4);
    int*   gstart  = (int*)p;   p += align256((size_t)(NUM_GRAPHS + 1) * 4);
    float* pooled  = (float*)p; p += align256((size_t)NUM_GRAPHS * HID * 4);
    int*   bsum    = (int*)p;   p += align256((size_t)SCAN_NB * 4);
    int*   bbase   = (int*)p;   p += align256((size_t)SCAN_NB * 4);
    short* Wth     = (short*)p; p += align256((size_t)3 * HID * HID * 2);
    short* Wtl     = (short*)p; p += align256((size_t)3 * HID * HID * 2);

    hipMemsetAsync(cnt, 0, (size_t)N_NODES * 4, stream);
    hipMemsetAsync(fillpos, 0, (size_t)N_NODES * 4, stream);

    const int TB = 256;
    k_count<<<(N_EDGES + TB - 1) / TB, TB, 0, stream>>>(ei, cnt);
    k_scan_part <<<SCAN_NB, 256, 0, stream>>>(cnt, bsum);
    k_scan_base <<<1, 256, 0, stream>>>(bsum, bbase);
    k_scan_final<<<SCAN_NB, 256, 0, stream>>>(cnt, bbase, offs, dis);
    k_fill<<<(N_EDGES + TB - 1) / TB, TB, 0, stream>>>(ei, offs, fillpos, csr);

    // splits
    int n4 = N_NODES * HID / 4;
    k_split<<<(n4 + TB - 1) / TB, TB, 0, stream>>>(x, bufAh, bufAl, n4);
    dim3 wg(64, 3);
    k_wsplit3<<<wg, 256, 0, stream>>>(W0, W1, W2, Wth, Wtl);

    int gemm_blocks = M_PAD / 64;             // 782
    int agg_blocks  = (N_NODES + 3) / 4;

    // layer 0
    k_gemm_mfma<<<gemm_blocks, 256, 0, stream>>>(bufAh, bufAl, Wth, Wtl,
                                                 th, tl, N_NODES, dis);
    k_agg<<<agg_blocks, 256, 0, stream>>>(th, tl, offs, csr, dis, b0,
                                          nullptr, bufBh, bufBl, 1);
    // layer 1
    k_gemm_mfma<<<gemm_blocks, 256, 0, stream>>>(bufBh, bufBl, Wth + HID * HID, Wtl + HID * HID,
                                                 th, tl, N_NODES, dis);
    k_agg<<<agg_blocks, 256, 0, stream>>>(th, tl, offs, csr, dis, b1,
                                          nullptr, bufAh, bufAl, 1);
    // layer 2 (no relu, fp32 out for pooling)
    k_gemm_mfma<<<gemm_blocks, 256, 0, stream>>>(bufAh, bufAl, Wth + 2 * HID * HID, Wtl + 2 * HID * HID,
                                                 th, tl, N_NODES, dis);
    k_agg<<<agg_blocks, 256, 0, stream>>>(th, tl, offs, csr, dis, b2,
                                          h, nullptr, nullptr, 0);

    k_bounds<<<(N_NODES + TB - 1) / TB, TB, 0, stream>>>(batch, gstart);
    k_pool<<<NUM_GRAPHS, 256, 0, stream>>>(h, gstart, pooled);
    k_ff<<<NUM_GRAPHS, 128, 0, stream>>>(pooled, Wf0, bf0, Wf1, bf1, out);
}